// Round 9
// baseline (357.828 us; speedup 1.0000x reference)
//
#include <hip/hip_runtime.h>
#include <hip/hip_bf16.h>

// ---------------------------------------------------------------------------
// FourDNet forward. Convs = bf16 MFMA implicit GEMM (NHWC). Folded chain:
//   v   = dep @ (W_merge_bot @ W_v) + c0v            [MFMA hi/lo split]
//   sel = sigmoid(F[:,1:] @ W_big + rowbias[b])      [MFMA hi/lo + fused softmax]
// WS rule (round 4): prep/folded buffers live outside ws[0..64MB] (c1 region).
// Round 9 lesson (r8 regression): B-frags per-MFMA from L2 = latency-bound
//   (MfmaUtil 7.5%). B must flow through LDS. Now: halo-A staged once +
//   pipelined B stage (prefetch regs during MFMA, 1-2 barriers/s, padded LDS).
// ---------------------------------------------------------------------------

typedef __attribute__((ext_vector_type(8))) short short8;
typedef __attribute__((ext_vector_type(4))) short shortx4;
typedef __attribute__((ext_vector_type(4))) float floatx4;

#define MFMA16(a, b, c) __builtin_amdgcn_mfma_f32_16x16x32_bf16(a, b, c, 0, 0, 0)

// ---- prep1: W_qs [256][72], W_mv [128][128], c0 [128], gfeat [64][128] ----
__global__ __launch_bounds__(256) void prep1_k(
    const float* __restrict__ W_q, const float* __restrict__ W_sel,
    const float* __restrict__ W_merge, const float* __restrict__ W_v,
    const float* __restrict__ g_depth, const float* __restrict__ b_merge,
    const float* __restrict__ features, const float* __restrict__ W_rg,
    const float* __restrict__ b_rg,
    float* __restrict__ W_qs, float* __restrict__ W_mv,
    float* __restrict__ c0, float* __restrict__ gfeat)
{
    int bid = blockIdx.x, t = threadIdx.x;
    if (bid < 72) {
        int j = bid;
        float acc = 0.f;
        for (int k = 0; k < 128; ++k)
            acc = fmaf(W_q[t * 128 + k], W_sel[k * 72 + j], acc);
        W_qs[t * 72 + j] = acc;
    } else if (bid < 200) {
        int j = bid - 72;
        if (t < 128) {
            float acc = 0.f;
            for (int k = 0; k < 128; ++k)
                acc = fmaf(W_merge[(128 + t) * 128 + k], W_v[k * 128 + j], acc);
            W_mv[t * 128 + j] = acc;
        }
    } else if (bid == 200) {
        if (t < 128) {
            float acc = b_merge[t];
            for (int k = 0; k < 128; ++k)
                acc = fmaf(g_depth[k], W_merge[k * 128 + t], acc);
            c0[t] = acc;
        }
    } else {
        int j = bid - 201;
        if (t < 64) {
            float acc = b_rg[j];
            const float* fr = features + (long)t * 129 * 768;
            for (int k = 0; k < 768; ++k)
                acc = fmaf(fr[k], W_rg[k * 128 + j], acc);
            gfeat[t * 128 + j] = acc;
        }
    }
}

// ---- prep2: W_big [768][72], rowbias [64][72], c0v [128] ----
__global__ __launch_bounds__(256) void prep2_k(
    const float* __restrict__ W_rl, const float* __restrict__ W_qs,
    const float* __restrict__ W_sel, const float* __restrict__ b_rl,
    const float* __restrict__ b_q, const float* __restrict__ b_sel,
    const float* __restrict__ gfeat, const float* __restrict__ c0,
    const float* __restrict__ W_v, const float* __restrict__ b_v,
    float* __restrict__ W_big, float* __restrict__ rowbias,
    float* __restrict__ c0v)
{
    int bid = blockIdx.x, t = threadIdx.x;
    if (bid < 216) {
        int j = bid / 3;
        int i = (bid % 3) * 256 + t;
        float acc = 0.f;
        for (int k = 0; k < 128; ++k)
            acc = fmaf(W_rl[i * 128 + k], W_qs[(128 + k) * 72 + j], acc);
        W_big[i * 72 + j] = acc;
    } else if (bid < 288) {
        int j = bid - 216;
        if (t < 64) {
            float vb = b_sel[j];
            for (int k = 0; k < 128; ++k) {
                vb = fmaf(b_rl[k], W_qs[(128 + k) * 72 + j], vb);
                vb = fmaf(b_q[k], W_sel[k * 72 + j], vb);
            }
            float acc = vb;
            for (int k = 0; k < 128; ++k)
                acc = fmaf(gfeat[t * 128 + k], W_qs[k * 72 + j], acc);
            rowbias[t * 72 + j] = acc;
        }
    } else {
        if (t < 128) {
            float acc = b_v[t];
            for (int k = 0; k < 128; ++k)
                acc = fmaf(c0[k], W_v[k * 128 + t], acc);
            c0v[t] = acc;
        }
    }
}

// ---- prep3: W_mv -> B-transposed bf16 hi/lo [n][k] ----
__global__ __launch_bounds__(256) void prep3_k(
    const float* __restrict__ W_mv,
    __hip_bfloat16* __restrict__ Bh, __hip_bfloat16* __restrict__ Bl)
{
    int idx = blockIdx.x * 256 + threadIdx.x;   // 16384
    int n = idx >> 7, k = idx & 127;
    float w = W_mv[k * 128 + n];
    __hip_bfloat16 h = __float2bfloat16(w);
    Bh[idx] = h;
    Bl[idx] = __float2bfloat16(w - __bfloat162float(h));
}

// ---- prep4: W_big [768][72] -> bf16 hi/lo [80][768] (n-major, cols>=72 zero)
__global__ __launch_bounds__(256) void prep4_k(
    const float* __restrict__ W_big,
    __hip_bfloat16* __restrict__ Wbh, __hip_bfloat16* __restrict__ Wbl)
{
    int idx = blockIdx.x * 256 + threadIdx.x;   // 80*768 = 61440
    if (idx >= 80 * 768) return;
    int n = idx / 768, k = idx - n * 768;
    float w = (n < 72) ? W_big[k * 72 + n] : 0.f;
    __hip_bfloat16 h = __float2bfloat16(w);
    Wbh[idx] = h;
    Wbl[idx] = __float2bfloat16(w - __bfloat162float(h));
}

// weight transform: OIHW fp32 -> [oc][(kh*3+kw)*IC + ic] bf16
__global__ __launch_bounds__(256) void wt2_k(const float* __restrict__ w,
                                             __hip_bfloat16* __restrict__ wt)
{
    int idx = blockIdx.x * 256 + threadIdx.x;
    if (idx >= 128 * 576) return;
    int oc = idx / 576, k = idx % 576;
    int s = k >> 6, ic = k & 63;
    wt[idx] = __float2bfloat16(w[oc * 576 + ic * 9 + s]);
}
__global__ __launch_bounds__(256) void wt3_k(const float* __restrict__ w,
                                             __hip_bfloat16* __restrict__ wt)
{
    int idx = blockIdx.x * 256 + threadIdx.x;
    if (idx >= 128 * 1152) return;
    int oc = idx / 1152, k = idx % 1152;
    int s = k >> 7, ic = k & 127;
    wt[idx] = __float2bfloat16(w[oc * 1152 + ic * 9 + s]);
}

// conv1: d (64,1,256,128) f32 -> out NHWC (64,128,64,64) bf16. stride2 pad1.
__global__ __launch_bounds__(256) void conv1_k(
    const float* __restrict__ d, const float* __restrict__ w,
    const float* __restrict__ bias, __hip_bfloat16* __restrict__ out)
{
    __shared__ float in_s[3][66];
    __shared__ float ws_[576];
    __shared__ float bs_[64];
    int tid = threadIdx.x;
    int owhalf = blockIdx.x & 1;
    int oh = (blockIdx.x >> 1) & 127;
    int b  = blockIdx.x >> 8;
    int owbase = owhalf * 32;

    for (int l = tid; l < 576; l += 256) ws_[l] = w[l];
    if (tid < 64) bs_[tid] = bias[tid];
    for (int l = tid; l < 3 * 66; l += 256) {
        int r = l / 66, c = l % 66;
        int ih = 2 * oh - 1 + r;
        int iw = 2 * owbase - 1 + c;
        float v = 0.f;
        if ((unsigned)ih < 256u && (unsigned)iw < 128u)
            v = d[(b * 256 + ih) * 128 + iw];
        in_s[r][c] = v;
    }
    __syncthreads();

    int owl = tid >> 3, ocg = tid & 7;
    float in9[9];
#pragma unroll
    for (int r = 0; r < 3; ++r)
#pragma unroll
        for (int c = 0; c < 3; ++c)
            in9[r * 3 + c] = in_s[r][2 * owl + c];

    short8 res;
#pragma unroll
    for (int j = 0; j < 8; ++j) {
        int oc = ocg * 8 + j;
        float a = bs_[oc];
#pragma unroll
        for (int s = 0; s < 9; ++s) a = fmaf(in9[s], ws_[oc * 9 + s], a);
        union { __hip_bfloat16 h; short s; } u;
        u.h = __float2bfloat16(a);
        res[j] = u.s;
    }
    long pos = ((long)(b * 128 + oh) * 64 + owbase + owl);
    *(short8*)((short*)out + pos * 64 + ocg * 8) = res;
}

// conv2 MFMA: in NHWC (64,128,64,64) bf16, w2t [128][576] bf16
//            -> out NHWC (64,64,32,128) bf16
// Halo-A staged once (padded, conflict-free); B double-buffered LDS with
// register prefetch pipelined under MFMA; 1 barrier per s.
__global__ __launch_bounds__(256) void conv2_mfma(
    const __hip_bfloat16* __restrict__ in, const __hip_bfloat16* __restrict__ w2t,
    const float* __restrict__ bias, __hip_bfloat16* __restrict__ out)
{
    __shared__ short ins[5][66][68];      // 44,880 B
    __shared__ short Bl2[2][128][68];     // 34,816 B  (total 79.7 KB -> 2 blk/CU)
    int tid = threadIdx.x;
    int oh0 = blockIdx.x * 2;
    int b   = blockIdx.y;
    const short* inp = (const short*)in;
    const short* w2p = (const short*)w2t;
    int ih0 = 2 * oh0 - 1;

    for (int l = tid; l < 330 * 8; l += 256) {
        int seg = l & 7, pos = l >> 3;
        int rr = pos / 66, cc = pos - rr * 66;
        int ih = ih0 + rr, iw = cc - 1;
        short8 v = {0,0,0,0,0,0,0,0};
        if ((unsigned)ih < 128u && (unsigned)iw < 64u)
            v = *(const short8*)(inp + ((((long)b * 128 + ih) * 64 + iw) * 64 + seg * 8));
        *(short8*)&ins[rr][cc][seg * 8] = v;
    }
    // B stage s=0: thread -> oc=tid>>1, k-half=(tid&1)*32 (64 B)
    int boc = tid >> 1, bk = (tid & 1) * 32;
    const short* bsrc = w2p + boc * 576 + bk;
    {
        short8 b0 = *(const short8*)(bsrc);
        short8 b1 = *(const short8*)(bsrc + 8);
        short8 b2 = *(const short8*)(bsrc + 16);
        short8 b3 = *(const short8*)(bsrc + 24);
        *(short8*)&Bl2[0][boc][bk]      = b0;
        *(short8*)&Bl2[0][boc][bk + 8]  = b1;
        *(short8*)&Bl2[0][boc][bk + 16] = b2;
        *(short8*)&Bl2[0][boc][bk + 24] = b3;
    }
    __syncthreads();

    int lane = tid & 63, wave = tid >> 6;
    int wr = wave >> 1, wc = wave & 1;
    int l16 = lane & 15, lh = lane >> 4;
    floatx4 acc[2][4] = {};

    int pos0 = wr * 32 + l16;
    int pos1 = pos0 + 16;
    int oa0 = pos0 >> 5, ow0 = pos0 & 31;
    int oa1 = pos1 >> 5, ow1 = pos1 & 31;

    for (int s = 0; s < 9; ++s) {
        short8 p0, p1, p2, p3;
        if (s < 8) {                       // prefetch B(s+1) into regs
            const short* ns = bsrc + (s + 1) * 64;
            p0 = *(const short8*)(ns);
            p1 = *(const short8*)(ns + 8);
            p2 = *(const short8*)(ns + 16);
            p3 = *(const short8*)(ns + 24);
        }
        int kh = s / 3, kw = s - kh * 3;
        const short* a0p = &ins[2 * oa0 + kh][2 * ow0 + kw][0];
        const short* a1p = &ins[2 * oa1 + kh][2 * ow1 + kw][0];
        const short (*Bc)[68] = Bl2[s & 1];
#pragma unroll
        for (int half = 0; half < 2; ++half) {
            short8 a0 = *(const short8*)(a0p + half * 32 + lh * 8);
            short8 a1 = *(const short8*)(a1p + half * 32 + lh * 8);
#pragma unroll
            for (int ni = 0; ni < 4; ++ni) {
                int gn = wc * 64 + ni * 16 + l16;
                short8 bv = *(const short8*)&Bc[gn][half * 32 + lh * 8];
                acc[0][ni] = MFMA16(a0, bv, acc[0][ni]);
                acc[1][ni] = MFMA16(a1, bv, acc[1][ni]);
            }
        }
        if (s < 8) {                       // write prefetched B to other buffer
            short* dst = &Bl2[(s + 1) & 1][boc][bk];
            *(short8*)(dst)      = p0;
            *(short8*)(dst + 8)  = p1;
            *(short8*)(dst + 16) = p2;
            *(short8*)(dst + 24) = p3;
        }
        __syncthreads();
    }

    float bf[4];
#pragma unroll
    for (int ni = 0; ni < 4; ++ni) bf[ni] = bias[wc * 64 + ni * 16 + l16];
#pragma unroll
    for (int mi = 0; mi < 2; ++mi)
#pragma unroll
        for (int r = 0; r < 4; ++r) {
            int m = wr * 32 + mi * 16 + lh * 4 + r;
            int ohl = m >> 5, ow = m & 31;
            __hip_bfloat16* op = out + (((long)(b * 64 + oh0 + ohl) * 32) + ow) * 128;
#pragma unroll
            for (int ni = 0; ni < 4; ++ni) {
                int oc = wc * 64 + ni * 16 + l16;
                op[oc] = __float2bfloat16(acc[mi][ni][r] + bf[ni]);
            }
        }
}

// conv3 MFMA: in NHWC (64,64,32,128) bf16, w3t [128][1152] bf16
//            -> dep (64*512, 128) fp32
// Halo-A staged once; B single-buffer LDS with register prefetch (2 barriers/s).
__global__ __launch_bounds__(256) void conv3_mfma(
    const __hip_bfloat16* __restrict__ in, const __hip_bfloat16* __restrict__ w3t,
    const float* __restrict__ bias, float* __restrict__ dep)
{
    __shared__ short ins[5][34][132];     // 44,880 B
    __shared__ short Bl3[128][132];       // 33,792 B (total 78.7 KB -> 2 blk/CU)
    int tid = threadIdx.x;
    int oh0 = blockIdx.x * 2;
    int b   = blockIdx.y;
    const short* inp = (const short*)in;
    const short* w3p = (const short*)w3t;
    int ih0 = 2 * oh0 - 1;

    for (int l = tid; l < 170 * 16; l += 256) {
        int seg = l & 15, pos = l >> 4;
        int rr = pos / 34, cc = pos - rr * 34;
        int ih = ih0 + rr, iw = cc - 1;
        short8 v = {0,0,0,0,0,0,0,0};
        if ((unsigned)ih < 64u && (unsigned)iw < 32u)
            v = *(const short8*)(inp + ((((long)b * 64 + ih) * 32 + iw) * 128 + seg * 8));
        *(short8*)&ins[rr][cc][seg * 8] = v;
    }
    // B stage s=0: thread -> oc=tid>>1, k-half=(tid&1)*64 (128 B)
    int boc = tid >> 1, bk = (tid & 1) * 64;
    const short* bsrc = w3p + boc * 1152 + bk;
#pragma unroll
    for (int i = 0; i < 8; ++i)
        *(short8*)&Bl3[boc][bk + i * 8] = *(const short8*)(bsrc + i * 8);
    __syncthreads();

    int lane = tid & 63, wave = tid >> 6;
    int wr = wave >> 1, wc = wave & 1;
    int l16 = lane & 15, lh = lane >> 4;
    floatx4 acc[4] = {};

    int pos = wr * 16 + l16;
    int oa = pos >> 4, ow = pos & 15;

    for (int s = 0; s < 9; ++s) {
        short8 p0, p1, p2, p3, p4, p5, p6, p7;
        if (s < 8) {                       // prefetch B(s+1)
            const short* ns = bsrc + (s + 1) * 128;
            p0 = *(const short8*)(ns);       p1 = *(const short8*)(ns + 8);
            p2 = *(const short8*)(ns + 16);  p3 = *(const short8*)(ns + 24);
            p4 = *(const short8*)(ns + 32);  p5 = *(const short8*)(ns + 40);
            p6 = *(const short8*)(ns + 48);  p7 = *(const short8*)(ns + 56);
        }
        int kh = s / 3, kw = s - kh * 3;
        const short* ap = &ins[2 * oa + kh][2 * ow + kw][0];
#pragma unroll
        for (int ks = 0; ks < 4; ++ks) {
            short8 a = *(const short8*)(ap + ks * 32 + lh * 8);
#pragma unroll
            for (int ni = 0; ni < 4; ++ni) {
                int gn = wc * 64 + ni * 16 + l16;
                short8 bv = *(const short8*)&Bl3[gn][ks * 32 + lh * 8];
                acc[ni] = MFMA16(a, bv, acc[ni]);
            }
        }
        __syncthreads();                   // all reads of Bl3 complete
        if (s < 8) {
            short* dst = &Bl3[boc][bk];
            *(short8*)(dst)      = p0; *(short8*)(dst + 8)  = p1;
            *(short8*)(dst + 16) = p2; *(short8*)(dst + 24) = p3;
            *(short8*)(dst + 32) = p4; *(short8*)(dst + 40) = p5;
            *(short8*)(dst + 48) = p6; *(short8*)(dst + 56) = p7;
            __syncthreads();               // writes visible for next s
        }
    }

    float bf[4];
#pragma unroll
    for (int ni = 0; ni < 4; ++ni) bf[ni] = bias[wc * 64 + ni * 16 + l16];
#pragma unroll
    for (int r = 0; r < 4; ++r) {
        int m = wr * 16 + lh * 4 + r;
        int oa2 = m >> 4, ow2 = m & 15;
        float* op = dep + ((long)b * 512 + (oh0 + oa2) * 16 + ow2) * 128;
#pragma unroll
        for (int ni = 0; ni < 4; ++ni) {
            int oc = wc * 64 + ni * 16 + l16;
            op[oc] = acc[ni][r] + bf[ni];
        }
    }
}

// v = dep @ W_mv + c0v via bf16 MFMA hi/lo split (~fp32 accuracy).
__global__ __launch_bounds__(256) void vgemm_mfma(
    const float* __restrict__ dep, const __hip_bfloat16* __restrict__ Bh,
    const __hip_bfloat16* __restrict__ Bl, const float* __restrict__ c0v,
    float* __restrict__ v)
{
    __shared__ short Ah[64][136];
    __shared__ short Al[64][136];
    int tid = threadIdx.x;
    int m0 = blockIdx.x * 64;

    for (int l4 = tid; l4 < 64 * 32; l4 += 256) {
        int r = l4 >> 5, c4 = l4 & 31;
        const float* sp = dep + ((long)(m0 + r) << 7) + c4 * 4;
        shortx4 hv, lv;
#pragma unroll
        for (int i = 0; i < 4; ++i) {
            float f = sp[i];
            union { __hip_bfloat16 b; short s; } uh, ul;
            uh.b = __float2bfloat16(f);
            ul.b = __float2bfloat16(f - __bfloat162float(uh.b));
            hv[i] = uh.s; lv[i] = ul.s;
        }
        *(shortx4*)&Ah[r][c4 * 4] = hv;
        *(shortx4*)&Al[r][c4 * 4] = lv;
    }
    __syncthreads();

    int lane = tid & 63, wave = tid >> 6;
    int wr = wave >> 1, wc = wave & 1;
    int l16 = lane & 15, lh = lane >> 4;
    floatx4 acc[2][4] = {};
#pragma unroll
    for (int kk = 0; kk < 4; ++kk) {
        short8 ah[2], al[2];
#pragma unroll
        for (int mi = 0; mi < 2; ++mi) {
            ah[mi] = *(const short8*)&Ah[wr * 32 + mi * 16 + l16][kk * 32 + lh * 8];
            al[mi] = *(const short8*)&Al[wr * 32 + mi * 16 + l16][kk * 32 + lh * 8];
        }
#pragma unroll
        for (int nf = 0; nf < 4; ++nf) {
            int gn = wc * 64 + nf * 16 + l16;
            short8 bh = *(const short8*)((const short*)Bh + gn * 128 + kk * 32 + lh * 8);
            short8 bl = *(const short8*)((const short*)Bl + gn * 128 + kk * 32 + lh * 8);
#pragma unroll
            for (int mi = 0; mi < 2; ++mi) {
                acc[mi][nf] = MFMA16(ah[mi], bh, acc[mi][nf]);
                acc[mi][nf] = MFMA16(al[mi], bh, acc[mi][nf]);
                acc[mi][nf] = MFMA16(ah[mi], bl, acc[mi][nf]);
            }
        }
    }
#pragma unroll
    for (int nf = 0; nf < 4; ++nf) {
        int gn = wc * 64 + nf * 16 + l16;
        float cv = c0v[gn];
#pragma unroll
        for (int mi = 0; mi < 2; ++mi)
#pragma unroll
            for (int r = 0; r < 4; ++r) {
                int m = m0 + wr * 32 + mi * 16 + lh * 4 + r;
                v[(long)m * 128 + gn] = acc[mi][nf][r] + cv;
            }
    }
}

// sel: MFMA hi/lo GEMM (8192 x 80pad x 768) + fused sigmoid + softmax.
__global__ __launch_bounds__(256) void selmfma_k(
    const float* __restrict__ F, const __hip_bfloat16* __restrict__ Wbh,
    const __hip_bfloat16* __restrict__ Wbl, const float* __restrict__ rowbias,
    float* __restrict__ lx, float* __restrict__ ly, float* __restrict__ attn)
{
    __shared__ short Ah[16][136];
    __shared__ short Al[16][136];
    int tid = threadIdx.x;
    int m0 = blockIdx.x * 16;
    int padd = (m0 >> 7) + 1;
    int lane = tid & 63, wave = tid >> 6;
    int l16 = lane & 15, lh = lane >> 4;

    int sr = tid >> 4, sc = (tid & 15) * 8;
    const float* fsrc = F + (long)(m0 + sr + padd) * 768 + sc;

    floatx4 acc0 = {0.f, 0.f, 0.f, 0.f};
    floatx4 acc1 = {0.f, 0.f, 0.f, 0.f};
    bool two = (wave == 3);
    const short* bhp = (const short*)Wbh;
    const short* blp = (const short*)Wbl;
    int gn0 = wave * 16 + l16;
    int gn1 = 64 + l16;

    for (int c = 0; c < 6; ++c) {
        __syncthreads();
        float4 f0 = *(const float4*)(fsrc + c * 128);
        float4 f1 = *(const float4*)(fsrc + c * 128 + 4);
        shortx4 h0, l0, h1, l1;
#pragma unroll
        for (int i = 0; i < 4; ++i) {
            union { __hip_bfloat16 b; short s; } uh, ul;
            float fa = (&f0.x)[i];
            uh.b = __float2bfloat16(fa);
            ul.b = __float2bfloat16(fa - __bfloat162float(uh.b));
            h0[i] = uh.s; l0[i] = ul.s;
            float fb = (&f1.x)[i];
            uh.b = __float2bfloat16(fb);
            ul.b = __float2bfloat16(fb - __bfloat162float(uh.b));
            h1[i] = uh.s; l1[i] = ul.s;
        }
        *(shortx4*)&Ah[sr][sc]     = h0;
        *(shortx4*)&Ah[sr][sc + 4] = h1;
        *(shortx4*)&Al[sr][sc]     = l0;
        *(shortx4*)&Al[sr][sc + 4] = l1;
        __syncthreads();
#pragma unroll
        for (int ks = 0; ks < 4; ++ks) {
            short8 ah = *(const short8*)&Ah[l16][ks * 32 + lh * 8];
            short8 al = *(const short8*)&Al[l16][ks * 32 + lh * 8];
            int koff = c * 128 + ks * 32 + lh * 8;
            short8 bh0 = *(const short8*)(bhp + gn0 * 768 + koff);
            short8 bl0 = *(const short8*)(blp + gn0 * 768 + koff);
            acc0 = MFMA16(ah, bh0, acc0);
            acc0 = MFMA16(al, bh0, acc0);
            acc0 = MFMA16(ah, bl0, acc0);
            if (two) {
                short8 bh1 = *(const short8*)(bhp + gn1 * 768 + koff);
                short8 bl1 = *(const short8*)(blp + gn1 * 768 + koff);
                acc1 = MFMA16(ah, bh1, acc1);
                acc1 = MFMA16(al, bh1, acc1);
                acc1 = MFMA16(ah, bl1, acc1);
            }
        }
    }

    if (wave < 3) {
        int j = wave * 16 + l16;
#pragma unroll
        for (int r = 0; r < 4; ++r) {
            int row = m0 + lh * 4 + r;
            float val = acc0[r] + rowbias[(row >> 7) * 72 + j];
            float sg = 1.f / (1.f + expf(-val));
            if (j & 1) ly[row * 24 + (j >> 1)] = sg;
            else       lx[row * 24 + (j >> 1)] = sg;
        }
    } else {
#pragma unroll
        for (int r = 0; r < 4; ++r) {
            int row = m0 + lh * 4 + r;
            int b72 = (row >> 7) * 72;
            float s0 = 1.f / (1.f + expf(-(acc0[r] + rowbias[b72 + 48 + l16])));
            float s1 = -1e30f;
            if (l16 < 8)
                s1 = 1.f / (1.f + expf(-(acc1[r] + rowbias[b72 + 64 + l16])));
            float mx = fmaxf(s0, s1);
#pragma unroll
            for (int s = 1; s < 16; s <<= 1)
                mx = fmaxf(mx, __shfl_xor(mx, s));
            float e0 = expf(s0 - mx);
            float e1 = (l16 < 8) ? expf(s1 - mx) : 0.f;
            float sum = e0 + e1;
#pragma unroll
            for (int s = 1; s < 16; s <<= 1)
                sum += __shfl_xor(sum, s);
            attn[row * 24 + l16] = e0 / sum;
            if (l16 < 8) attn[row * 24 + 16 + l16] = e1 / sum;
        }
    }
}

// bilinear gather + attn-weighted mean over 24 keypoints
__global__ __launch_bounds__(128) void r2d_k(
    const float* __restrict__ v, const float* __restrict__ lx,
    const float* __restrict__ ly, const float* __restrict__ attn,
    float* __restrict__ r2d)
{
    int n = blockIdx.x;
    int b = blockIdx.y;
    int c = threadIdx.x;
    int row = b * 128 + n;
    __shared__ float sx[24], sy[24], sa[24];
    if (c < 24) { sx[c] = lx[row * 24 + c]; sy[c] = ly[row * 24 + c]; sa[c] = attn[row * 24 + c]; }
    __syncthreads();
    const float* vb = v + (long)b * 512 * 128;
    float acc = 0.f;
    for (int k = 0; k < 24; ++k) {
        float lxv = sx[k], lyv = sy[k], a = sa[k];
        float x1 = floorf(lxv * 15.f), x2 = fminf(x1 + 1.f, 15.f);
        float y1 = floorf(lyv * 31.f), y2 = fminf(y1 + 1.f, 31.f);
        int xi1 = (int)x1, xi2 = (int)x2, yi1 = (int)y1, yi2 = (int)y2;
        float f0 = vb[(xi1 * 16 + yi2) * 128 + c];
        float f1 = vb[(xi2 * 16 + yi2) * 128 + c];
        float f2 = vb[(xi2 * 16 + yi1) * 128 + c];
        float f3 = vb[(xi1 * 16 + yi1) * 128 + c];
        float x = lxv * 16.f, y = lyv * 32.f;
        float w_ = x2 - x1, h_ = y2 - y1;
        float hwp = h_ * w_;
        bool deg = (h_ == 0.f) || (w_ == 0.f);
        float denom = (hwp == 0.f) ? 1.f : hwp;
        float coeff = deg ? 2.f : 1.f / denom;
        float xv0 = (w_ == 0.f) ? 1.f : (x2 - x);
        float xv1 = (w_ == 0.f) ? 1.f : (x - x1);
        float yv0 = (h_ == 0.f) ? 1.f : (y2 - y);
        float yv1 = (h_ == 0.f) ? 1.f : (y - y1);
        float interp = coeff * (xv0 * (f0 * yv0 + f1 * yv1) + xv1 * (f2 * yv0 + f3 * yv1));
        acc = fmaf(interp, a, acc);
    }
    r2d[(long)row * 128 + c] = acc * (1.f / 24.f);
}

// final_embedding[b,c] = mean over n of r2d
__global__ __launch_bounds__(128) void fe_k(const float* __restrict__ r2d,
                                            float* __restrict__ fe)
{
    int b = blockIdx.x;
    int c = threadIdx.x;
    float acc = 0.f;
    for (int nn = 0; nn < 128; ++nn) acc += r2d[((long)b * 128 + nn) * 128 + c];
    fe[b * 128 + c] = acc * (1.f / 128.f);
}

// cls_score = fe @ W_cls, thread-per-output
__global__ __launch_bounds__(256) void cls_k(
    const float* __restrict__ fe, const float* __restrict__ W_cls,
    float* __restrict__ out)
{
    int idx = blockIdx.x * 256 + threadIdx.x;
    if (idx >= 64 * 751) return;
    int m = idx / 751, n = idx - m * 751;
    const float* fr = fe + m * 128;
    float acc = 0.f;
    for (int k = 0; k < 128; ++k)
        acc = fmaf(fr[k], W_cls[k * 751 + n], acc);
    out[idx] = acc;
}

extern "C" void kernel_launch(void* const* d_in, const int* in_sizes, int n_in,
                              void* d_out, int out_size, void* d_ws, size_t ws_size,
                              hipStream_t stream)
{
    const float* features = (const float*)d_in[0];
    const float* d        = (const float*)d_in[1];
    const float* W_rg  = (const float*)d_in[2];
    const float* b_rg  = (const float*)d_in[3];
    const float* W_rl  = (const float*)d_in[4];
    const float* b_rl  = (const float*)d_in[5];
    const float* c1w   = (const float*)d_in[6];
    const float* c1b   = (const float*)d_in[7];
    const float* c2w   = (const float*)d_in[8];
    const float* c2b   = (const float*)d_in[9];
    const float* c3w   = (const float*)d_in[10];
    const float* c3b   = (const float*)d_in[11];
    const float* g_depth = (const float*)d_in[12];
    const float* W_merge = (const float*)d_in[13];
    const float* b_merge = (const float*)d_in[14];
    const float* W_q   = (const float*)d_in[15];
    const float* b_q   = (const float*)d_in[16];
    const float* W_v   = (const float*)d_in[17];
    const float* b_v   = (const float*)d_in[18];
    const float* W_sel = (const float*)d_in[19];
    const float* b_sel = (const float*)d_in[20];
    const float* W_cls = (const float*)d_in[21];
    float* out = (float*)d_out;

    char* ws = (char*)d_ws;
    __hip_bfloat16* c1 = (__hip_bfloat16*)(ws + 0);            // NHWC, ws[0 .. 67,108,864)
    float* dep    = (float*)(ws + 0);                          // 16,777,216 (c1 dead after conv2)
    float* v      = (float*)(ws + 33554432);                   // 16,777,216
    __hip_bfloat16* c2 = (__hip_bfloat16*)(ws + 67108864);     // NHWC 33,554,432
    __hip_bfloat16* w2t = (__hip_bfloat16*)(ws + 100663296);          // 147,456
    __hip_bfloat16* w3t = (__hip_bfloat16*)(ws + 100810752);          // 294,912
    // folded-weight buffers: dead gap, untouched by convs
    float* W_qs    = (float*)(ws + 101105664);                 // 73,728
    float* W_mv    = (float*)(ws + 101179392);                 // 65,536
    float* W_big   = (float*)(ws + 101244928);                 // 221,184
    float* rowbias = (float*)(ws + 101466112);                 // 18,432
    float* c0b     = (float*)(ws + 101484544);                 // 512
    float* c0v     = (float*)(ws + 101485056);                 // 512
    float* gfeat   = (float*)(ws + 101485568);                 // 32,768
    __hip_bfloat16* Wmv_bh = (__hip_bfloat16*)(ws + 101518336);  // 32,768
    __hip_bfloat16* Wmv_bl = (__hip_bfloat16*)(ws + 101551104);  // 32,768
    __hip_bfloat16* Wbig_h = (__hip_bfloat16*)(ws + 101583872);  // 122,880
    __hip_bfloat16* Wbig_l = (__hip_bfloat16*)(ws + 101706752);  // 122,880 (ends 101,829,632)
    float* lxb    = (float*)(ws + 111411200);                  // 786,432
    float* lyb    = (float*)(ws + 112197632);                  // 786,432
    float* attnb  = (float*)(ws + 112984064);                  // 786,432
    float* r2d    = (float*)(ws + 113836544);                  // 4,194,304

    float* fe = out + 64 * 751;

    // ---- prep (folded weights) ----
    prep1_k<<<329, 256, 0, stream>>>(W_q, W_sel, W_merge, W_v, g_depth, b_merge,
                                     features, W_rg, b_rg, W_qs, W_mv, c0b, gfeat);
    prep2_k<<<289, 256, 0, stream>>>(W_rl, W_qs, W_sel, b_rl, b_q, b_sel,
                                     gfeat, c0b, W_v, b_v, W_big, rowbias, c0v);
    prep3_k<<<64, 256, 0, stream>>>(W_mv, Wmv_bh, Wmv_bl);
    prep4_k<<<240, 256, 0, stream>>>(W_big, Wbig_h, Wbig_l);
    wt2_k<<<288, 256, 0, stream>>>(c2w, w2t);
    wt3_k<<<576, 256, 0, stream>>>(c3w, w3t);

    // ---- conv path (MFMA) ----
    conv1_k<<<16384, 256, 0, stream>>>(d, c1w, c1b, c1);
    conv2_mfma<<<dim3(32, 64), 256, 0, stream>>>(c1, w2t, c2b, c2);
    conv3_mfma<<<dim3(16, 64), 256, 0, stream>>>(c2, w3t, c3b, dep);

    // v = dep @ W_mv + c0v   (MFMA hi/lo)
    vgemm_mfma<<<512, 256, 0, stream>>>(dep, Wmv_bh, Wmv_bl, c0v, v);
    // sel (MFMA hi/lo GEMM + sigmoid + softmax fused)
    selmfma_k<<<512, 256, 0, stream>>>(features, Wbig_h, Wbig_l, rowbias,
                                       lxb, lyb, attnb);

    // ---- fusion tail ----
    r2d_k<<<dim3(128, 64), 128, 0, stream>>>(v, lxb, lyb, attnb, r2d);
    fe_k<<<64, 128, 0, stream>>>(r2d, fe);
    cls_k<<<188, 256, 0, stream>>>(fe, W_cls, out);
}

// Round 10
// 243.124 us; speedup vs baseline: 1.4718x; 1.4718x over previous
//
#include <hip/hip_runtime.h>
#include <hip/hip_bf16.h>

// ---------------------------------------------------------------------------
// FourDNet forward. Convs = bf16 MFMA implicit GEMM (NHWC). Folded chain:
//   v   = dep @ (W_merge_bot @ W_v) + c0v            [MFMA hi/lo split]
//   sel = sigmoid(F[:,1:] @ W_big + rowbias[b])      [MFMA hi/lo + fused softmax]
// WS rule (round 4): prep/folded buffers live outside ws[0..64MB] (c1 region).
// Round 10: conv2/3 REVERTED to round-7 structure (41us, 12KB LDS, 5 blk/CU —
//   occupancy beats pipelining at this work size; r8 L2-direct=95us and r9
//   halo+dbuf=120us both regressed). Single fix: LDS rows padded 32->40 shorts
//   (20 dwords): 8 consecutive rows hit bank-groups {0,20,8,28,16,4,24,12} =
//   all 32 banks -> frag ds_read_b128 conflict-free (was 4-way, 3.5M conflicts).
// ---------------------------------------------------------------------------

typedef __attribute__((ext_vector_type(8))) short short8;
typedef __attribute__((ext_vector_type(4))) short shortx4;
typedef __attribute__((ext_vector_type(4))) float floatx4;

#define MFMA16(a, b, c) __builtin_amdgcn_mfma_f32_16x16x32_bf16(a, b, c, 0, 0, 0)

// ---- prep1: W_qs [256][72], W_mv [128][128], c0 [128], gfeat [64][128] ----
__global__ __launch_bounds__(256) void prep1_k(
    const float* __restrict__ W_q, const float* __restrict__ W_sel,
    const float* __restrict__ W_merge, const float* __restrict__ W_v,
    const float* __restrict__ g_depth, const float* __restrict__ b_merge,
    const float* __restrict__ features, const float* __restrict__ W_rg,
    const float* __restrict__ b_rg,
    float* __restrict__ W_qs, float* __restrict__ W_mv,
    float* __restrict__ c0, float* __restrict__ gfeat)
{
    int bid = blockIdx.x, t = threadIdx.x;
    if (bid < 72) {
        int j = bid;
        float acc = 0.f;
        for (int k = 0; k < 128; ++k)
            acc = fmaf(W_q[t * 128 + k], W_sel[k * 72 + j], acc);
        W_qs[t * 72 + j] = acc;
    } else if (bid < 200) {
        int j = bid - 72;
        if (t < 128) {
            float acc = 0.f;
            for (int k = 0; k < 128; ++k)
                acc = fmaf(W_merge[(128 + t) * 128 + k], W_v[k * 128 + j], acc);
            W_mv[t * 128 + j] = acc;
        }
    } else if (bid == 200) {
        if (t < 128) {
            float acc = b_merge[t];
            for (int k = 0; k < 128; ++k)
                acc = fmaf(g_depth[k], W_merge[k * 128 + t], acc);
            c0[t] = acc;
        }
    } else {
        int j = bid - 201;
        if (t < 64) {
            float acc = b_rg[j];
            const float* fr = features + (long)t * 129 * 768;
            for (int k = 0; k < 768; ++k)
                acc = fmaf(fr[k], W_rg[k * 128 + j], acc);
            gfeat[t * 128 + j] = acc;
        }
    }
}

// ---- prep2: W_big [768][72], rowbias [64][72], c0v [128] ----
__global__ __launch_bounds__(256) void prep2_k(
    const float* __restrict__ W_rl, const float* __restrict__ W_qs,
    const float* __restrict__ W_sel, const float* __restrict__ b_rl,
    const float* __restrict__ b_q, const float* __restrict__ b_sel,
    const float* __restrict__ gfeat, const float* __restrict__ c0,
    const float* __restrict__ W_v, const float* __restrict__ b_v,
    float* __restrict__ W_big, float* __restrict__ rowbias,
    float* __restrict__ c0v)
{
    int bid = blockIdx.x, t = threadIdx.x;
    if (bid < 216) {
        int j = bid / 3;
        int i = (bid % 3) * 256 + t;
        float acc = 0.f;
        for (int k = 0; k < 128; ++k)
            acc = fmaf(W_rl[i * 128 + k], W_qs[(128 + k) * 72 + j], acc);
        W_big[i * 72 + j] = acc;
    } else if (bid < 288) {
        int j = bid - 216;
        if (t < 64) {
            float vb = b_sel[j];
            for (int k = 0; k < 128; ++k) {
                vb = fmaf(b_rl[k], W_qs[(128 + k) * 72 + j], vb);
                vb = fmaf(b_q[k], W_sel[k * 72 + j], vb);
            }
            float acc = vb;
            for (int k = 0; k < 128; ++k)
                acc = fmaf(gfeat[t * 128 + k], W_qs[k * 72 + j], acc);
            rowbias[t * 72 + j] = acc;
        }
    } else {
        if (t < 128) {
            float acc = b_v[t];
            for (int k = 0; k < 128; ++k)
                acc = fmaf(c0[k], W_v[k * 128 + t], acc);
            c0v[t] = acc;
        }
    }
}

// ---- prep3: W_mv -> B-transposed bf16 hi/lo [n][k] ----
__global__ __launch_bounds__(256) void prep3_k(
    const float* __restrict__ W_mv,
    __hip_bfloat16* __restrict__ Bh, __hip_bfloat16* __restrict__ Bl)
{
    int idx = blockIdx.x * 256 + threadIdx.x;   // 16384
    int n = idx >> 7, k = idx & 127;
    float w = W_mv[k * 128 + n];
    __hip_bfloat16 h = __float2bfloat16(w);
    Bh[idx] = h;
    Bl[idx] = __float2bfloat16(w - __bfloat162float(h));
}

// ---- prep4: W_big [768][72] -> bf16 hi/lo [80][768] (n-major, cols>=72 zero)
__global__ __launch_bounds__(256) void prep4_k(
    const float* __restrict__ W_big,
    __hip_bfloat16* __restrict__ Wbh, __hip_bfloat16* __restrict__ Wbl)
{
    int idx = blockIdx.x * 256 + threadIdx.x;   // 80*768 = 61440
    if (idx >= 80 * 768) return;
    int n = idx / 768, k = idx - n * 768;
    float w = (n < 72) ? W_big[k * 72 + n] : 0.f;
    __hip_bfloat16 h = __float2bfloat16(w);
    Wbh[idx] = h;
    Wbl[idx] = __float2bfloat16(w - __bfloat162float(h));
}

// weight transform: OIHW fp32 -> [oc][(kh*3+kw)*IC + ic] bf16
__global__ __launch_bounds__(256) void wt2_k(const float* __restrict__ w,
                                             __hip_bfloat16* __restrict__ wt)
{
    int idx = blockIdx.x * 256 + threadIdx.x;
    if (idx >= 128 * 576) return;
    int oc = idx / 576, k = idx % 576;
    int s = k >> 6, ic = k & 63;
    wt[idx] = __float2bfloat16(w[oc * 576 + ic * 9 + s]);
}
__global__ __launch_bounds__(256) void wt3_k(const float* __restrict__ w,
                                             __hip_bfloat16* __restrict__ wt)
{
    int idx = blockIdx.x * 256 + threadIdx.x;
    if (idx >= 128 * 1152) return;
    int oc = idx / 1152, k = idx % 1152;
    int s = k >> 7, ic = k & 127;
    wt[idx] = __float2bfloat16(w[oc * 1152 + ic * 9 + s]);
}

// conv1: d (64,1,256,128) f32 -> out NHWC (64,128,64,64) bf16. stride2 pad1.
__global__ __launch_bounds__(256) void conv1_k(
    const float* __restrict__ d, const float* __restrict__ w,
    const float* __restrict__ bias, __hip_bfloat16* __restrict__ out)
{
    __shared__ float in_s[3][66];
    __shared__ float ws_[576];
    __shared__ float bs_[64];
    int tid = threadIdx.x;
    int owhalf = blockIdx.x & 1;
    int oh = (blockIdx.x >> 1) & 127;
    int b  = blockIdx.x >> 8;
    int owbase = owhalf * 32;

    for (int l = tid; l < 576; l += 256) ws_[l] = w[l];
    if (tid < 64) bs_[tid] = bias[tid];
    for (int l = tid; l < 3 * 66; l += 256) {
        int r = l / 66, c = l % 66;
        int ih = 2 * oh - 1 + r;
        int iw = 2 * owbase - 1 + c;
        float v = 0.f;
        if ((unsigned)ih < 256u && (unsigned)iw < 128u)
            v = d[(b * 256 + ih) * 128 + iw];
        in_s[r][c] = v;
    }
    __syncthreads();

    int owl = tid >> 3, ocg = tid & 7;
    float in9[9];
#pragma unroll
    for (int r = 0; r < 3; ++r)
#pragma unroll
        for (int c = 0; c < 3; ++c)
            in9[r * 3 + c] = in_s[r][2 * owl + c];

    short8 res;
#pragma unroll
    for (int j = 0; j < 8; ++j) {
        int oc = ocg * 8 + j;
        float a = bs_[oc];
#pragma unroll
        for (int s = 0; s < 9; ++s) a = fmaf(in9[s], ws_[oc * 9 + s], a);
        union { __hip_bfloat16 h; short s; } u;
        u.h = __float2bfloat16(a);
        res[j] = u.s;
    }
    long pos = ((long)(b * 128 + oh) * 64 + owbase + owl);
    *(short8*)((short*)out + pos * 64 + ocg * 8) = res;
}

// conv2 MFMA (round-7 structure + padded LDS): in NHWC (64,128,64,64) bf16,
// w2t [128][576] bf16 -> out NHWC (64,64,32,128) bf16
__global__ __launch_bounds__(256) void conv2_mfma(
    const __hip_bfloat16* __restrict__ in, const __hip_bfloat16* __restrict__ w2t,
    const float* __restrict__ bias, __hip_bfloat16* __restrict__ out)
{
    __shared__ short A_lds[64][40];    // 40 shorts = 20 dwords: conflict-free frag reads
    __shared__ short B_lds[128][40];
    int tid = threadIdx.x;
    int oh0 = blockIdx.x * 2;
    int b   = blockIdx.y;
    int lane = tid & 63, wave = tid >> 6;
    int wr = wave >> 1, wc = wave & 1;
    floatx4 acc[2][4] = {};

    int ar = tid >> 2, aseg = tid & 3;
    int aohl = ar >> 5, aow = ar & 31;
    int boc = tid >> 2, bseg = tid & 3;

    const short* inp  = (const short*)in;
    const short* w2p  = (const short*)w2t;

    for (int s = 0; s < 9; ++s) {
        int kh = s / 3, kw = s % 3;
        int ih = 2 * (oh0 + aohl) - 1 + kh;
        int iw = 2 * aow - 1 + kw;
        bool inb = ((unsigned)ih < 128u) & ((unsigned)iw < 64u);
        const short* asrc = inp + (((b * 128 + ih) * 64 + iw) * 64 + aseg * 8);
#pragma unroll
        for (int half = 0; half < 2; ++half) {
            int koff = s * 64 + half * 32;
            short8 av = {0,0,0,0,0,0,0,0};
            if (inb) av = *(const short8*)(asrc + half * 32);
            short8 bv0 = *(const short8*)(w2p + boc * 576 + koff + bseg * 8);
            short8 bv1 = *(const short8*)(w2p + (boc + 64) * 576 + koff + bseg * 8);
            __syncthreads();
            *(short8*)&A_lds[ar][aseg * 8] = av;
            *(short8*)&B_lds[boc][bseg * 8] = bv0;
            *(short8*)&B_lds[boc + 64][bseg * 8] = bv1;
            __syncthreads();
            short8 a0 = *(const short8*)&A_lds[wr * 32 + (lane & 15)][(lane >> 4) * 8];
            short8 a1 = *(const short8*)&A_lds[wr * 32 + 16 + (lane & 15)][(lane >> 4) * 8];
#pragma unroll
            for (int ni = 0; ni < 4; ++ni) {
                short8 bv = *(const short8*)&B_lds[wc * 64 + ni * 16 + (lane & 15)][(lane >> 4) * 8];
                acc[0][ni] = MFMA16(a0, bv, acc[0][ni]);
                acc[1][ni] = MFMA16(a1, bv, acc[1][ni]);
            }
        }
    }
    float bf[4];
#pragma unroll
    for (int ni = 0; ni < 4; ++ni) bf[ni] = bias[wc * 64 + ni * 16 + (lane & 15)];
#pragma unroll
    for (int mi = 0; mi < 2; ++mi)
#pragma unroll
        for (int r = 0; r < 4; ++r) {
            int m = wr * 32 + mi * 16 + (lane >> 4) * 4 + r;
            int ohl = m >> 5, ow = m & 31;
            __hip_bfloat16* op = out + (((long)(b * 64 + oh0 + ohl) * 32) + ow) * 128;
#pragma unroll
            for (int ni = 0; ni < 4; ++ni) {
                int oc = wc * 64 + ni * 16 + (lane & 15);
                op[oc] = __float2bfloat16(acc[mi][ni][r] + bf[ni]);
            }
        }
}

// conv3 MFMA (round-7 structure + padded LDS): in NHWC (64,64,32,128) bf16,
// w3t [128][1152] bf16 -> dep (64*512, 128) fp32
__global__ __launch_bounds__(256) void conv3_mfma(
    const __hip_bfloat16* __restrict__ in, const __hip_bfloat16* __restrict__ w3t,
    const float* __restrict__ bias, float* __restrict__ dep)
{
    __shared__ short A_lds[64][40];
    __shared__ short B_lds[128][40];
    int tid = threadIdx.x;
    int oh0 = blockIdx.x * 4;
    int b   = blockIdx.y;
    int lane = tid & 63, wave = tid >> 6;
    int wr = wave >> 1, wc = wave & 1;
    floatx4 acc[2][4] = {};

    int ar = tid >> 2, aseg = tid & 3;
    int aohl = ar >> 4, aow = ar & 15;
    int boc = tid >> 2, bseg = tid & 3;

    const short* inp = (const short*)in;
    const short* w3p = (const short*)w3t;

    for (int s = 0; s < 9; ++s) {
        int kh = s / 3, kw = s % 3;
        int ih = 2 * (oh0 + aohl) - 1 + kh;
        int iw = 2 * aow - 1 + kw;
        bool inb = ((unsigned)ih < 64u) & ((unsigned)iw < 32u);
        const short* asrc = inp + (((b * 64 + ih) * 32 + iw) * 128 + aseg * 8);
#pragma unroll
        for (int q = 0; q < 4; ++q) {
            int koff = s * 128 + q * 32;
            short8 av = {0,0,0,0,0,0,0,0};
            if (inb) av = *(const short8*)(asrc + q * 32);
            short8 bv0 = *(const short8*)(w3p + boc * 1152 + koff + bseg * 8);
            short8 bv1 = *(const short8*)(w3p + (boc + 64) * 1152 + koff + bseg * 8);
            __syncthreads();
            *(short8*)&A_lds[ar][aseg * 8] = av;
            *(short8*)&B_lds[boc][bseg * 8] = bv0;
            *(short8*)&B_lds[boc + 64][bseg * 8] = bv1;
            __syncthreads();
            short8 a0 = *(const short8*)&A_lds[wr * 32 + (lane & 15)][(lane >> 4) * 8];
            short8 a1 = *(const short8*)&A_lds[wr * 32 + 16 + (lane & 15)][(lane >> 4) * 8];
#pragma unroll
            for (int ni = 0; ni < 4; ++ni) {
                short8 bv = *(const short8*)&B_lds[wc * 64 + ni * 16 + (lane & 15)][(lane >> 4) * 8];
                acc[0][ni] = MFMA16(a0, bv, acc[0][ni]);
                acc[1][ni] = MFMA16(a1, bv, acc[1][ni]);
            }
        }
    }
    float bf[4];
#pragma unroll
    for (int ni = 0; ni < 4; ++ni) bf[ni] = bias[wc * 64 + ni * 16 + (lane & 15)];
#pragma unroll
    for (int mi = 0; mi < 2; ++mi)
#pragma unroll
        for (int r = 0; r < 4; ++r) {
            int m = wr * 32 + mi * 16 + (lane >> 4) * 4 + r;
            float* op = dep + ((long)b * 512 + oh0 * 16 + m) * 128;
#pragma unroll
            for (int ni = 0; ni < 4; ++ni) {
                int oc = wc * 64 + ni * 16 + (lane & 15);
                op[oc] = acc[mi][ni][r] + bf[ni];
            }
        }
}

// v = dep @ W_mv + c0v via bf16 MFMA hi/lo split (~fp32 accuracy).
__global__ __launch_bounds__(256) void vgemm_mfma(
    const float* __restrict__ dep, const __hip_bfloat16* __restrict__ Bh,
    const __hip_bfloat16* __restrict__ Bl, const float* __restrict__ c0v,
    float* __restrict__ v)
{
    __shared__ short Ah[64][136];
    __shared__ short Al[64][136];
    int tid = threadIdx.x;
    int m0 = blockIdx.x * 64;

    for (int l4 = tid; l4 < 64 * 32; l4 += 256) {
        int r = l4 >> 5, c4 = l4 & 31;
        const float* sp = dep + ((long)(m0 + r) << 7) + c4 * 4;
        shortx4 hv, lv;
#pragma unroll
        for (int i = 0; i < 4; ++i) {
            float f = sp[i];
            union { __hip_bfloat16 b; short s; } uh, ul;
            uh.b = __float2bfloat16(f);
            ul.b = __float2bfloat16(f - __bfloat162float(uh.b));
            hv[i] = uh.s; lv[i] = ul.s;
        }
        *(shortx4*)&Ah[r][c4 * 4] = hv;
        *(shortx4*)&Al[r][c4 * 4] = lv;
    }
    __syncthreads();

    int lane = tid & 63, wave = tid >> 6;
    int wr = wave >> 1, wc = wave & 1;
    int l16 = lane & 15, lh = lane >> 4;
    floatx4 acc[2][4] = {};
#pragma unroll
    for (int kk = 0; kk < 4; ++kk) {
        short8 ah[2], al[2];
#pragma unroll
        for (int mi = 0; mi < 2; ++mi) {
            ah[mi] = *(const short8*)&Ah[wr * 32 + mi * 16 + l16][kk * 32 + lh * 8];
            al[mi] = *(const short8*)&Al[wr * 32 + mi * 16 + l16][kk * 32 + lh * 8];
        }
#pragma unroll
        for (int nf = 0; nf < 4; ++nf) {
            int gn = wc * 64 + nf * 16 + l16;
            short8 bh = *(const short8*)((const short*)Bh + gn * 128 + kk * 32 + lh * 8);
            short8 bl = *(const short8*)((const short*)Bl + gn * 128 + kk * 32 + lh * 8);
#pragma unroll
            for (int mi = 0; mi < 2; ++mi) {
                acc[mi][nf] = MFMA16(ah[mi], bh, acc[mi][nf]);
                acc[mi][nf] = MFMA16(al[mi], bh, acc[mi][nf]);
                acc[mi][nf] = MFMA16(ah[mi], bl, acc[mi][nf]);
            }
        }
    }
#pragma unroll
    for (int nf = 0; nf < 4; ++nf) {
        int gn = wc * 64 + nf * 16 + l16;
        float cv = c0v[gn];
#pragma unroll
        for (int mi = 0; mi < 2; ++mi)
#pragma unroll
            for (int r = 0; r < 4; ++r) {
                int m = m0 + wr * 32 + mi * 16 + lh * 4 + r;
                v[(long)m * 128 + gn] = acc[mi][nf][r] + cv;
            }
    }
}

// sel: MFMA hi/lo GEMM (8192 x 80pad x 768) + fused sigmoid + softmax.
__global__ __launch_bounds__(256) void selmfma_k(
    const float* __restrict__ F, const __hip_bfloat16* __restrict__ Wbh,
    const __hip_bfloat16* __restrict__ Wbl, const float* __restrict__ rowbias,
    float* __restrict__ lx, float* __restrict__ ly, float* __restrict__ attn)
{
    __shared__ short Ah[16][136];
    __shared__ short Al[16][136];
    int tid = threadIdx.x;
    int m0 = blockIdx.x * 16;
    int padd = (m0 >> 7) + 1;
    int lane = tid & 63, wave = tid >> 6;
    int l16 = lane & 15, lh = lane >> 4;

    int sr = tid >> 4, sc = (tid & 15) * 8;
    const float* fsrc = F + (long)(m0 + sr + padd) * 768 + sc;

    floatx4 acc0 = {0.f, 0.f, 0.f, 0.f};
    floatx4 acc1 = {0.f, 0.f, 0.f, 0.f};
    bool two = (wave == 3);
    const short* bhp = (const short*)Wbh;
    const short* blp = (const short*)Wbl;
    int gn0 = wave * 16 + l16;
    int gn1 = 64 + l16;

    for (int c = 0; c < 6; ++c) {
        __syncthreads();
        float4 f0 = *(const float4*)(fsrc + c * 128);
        float4 f1 = *(const float4*)(fsrc + c * 128 + 4);
        shortx4 h0, l0, h1, l1;
#pragma unroll
        for (int i = 0; i < 4; ++i) {
            union { __hip_bfloat16 b; short s; } uh, ul;
            float fa = (&f0.x)[i];
            uh.b = __float2bfloat16(fa);
            ul.b = __float2bfloat16(fa - __bfloat162float(uh.b));
            h0[i] = uh.s; l0[i] = ul.s;
            float fb = (&f1.x)[i];
            uh.b = __float2bfloat16(fb);
            ul.b = __float2bfloat16(fb - __bfloat162float(uh.b));
            h1[i] = uh.s; l1[i] = ul.s;
        }
        *(shortx4*)&Ah[sr][sc]     = h0;
        *(shortx4*)&Ah[sr][sc + 4] = h1;
        *(shortx4*)&Al[sr][sc]     = l0;
        *(shortx4*)&Al[sr][sc + 4] = l1;
        __syncthreads();
#pragma unroll
        for (int ks = 0; ks < 4; ++ks) {
            short8 ah = *(const short8*)&Ah[l16][ks * 32 + lh * 8];
            short8 al = *(const short8*)&Al[l16][ks * 32 + lh * 8];
            int koff = c * 128 + ks * 32 + lh * 8;
            short8 bh0 = *(const short8*)(bhp + gn0 * 768 + koff);
            short8 bl0 = *(const short8*)(blp + gn0 * 768 + koff);
            acc0 = MFMA16(ah, bh0, acc0);
            acc0 = MFMA16(al, bh0, acc0);
            acc0 = MFMA16(ah, bl0, acc0);
            if (two) {
                short8 bh1 = *(const short8*)(bhp + gn1 * 768 + koff);
                short8 bl1 = *(const short8*)(blp + gn1 * 768 + koff);
                acc1 = MFMA16(ah, bh1, acc1);
                acc1 = MFMA16(al, bh1, acc1);
                acc1 = MFMA16(ah, bl1, acc1);
            }
        }
    }

    if (wave < 3) {
        int j = wave * 16 + l16;
#pragma unroll
        for (int r = 0; r < 4; ++r) {
            int row = m0 + lh * 4 + r;
            float val = acc0[r] + rowbias[(row >> 7) * 72 + j];
            float sg = 1.f / (1.f + expf(-val));
            if (j & 1) ly[row * 24 + (j >> 1)] = sg;
            else       lx[row * 24 + (j >> 1)] = sg;
        }
    } else {
#pragma unroll
        for (int r = 0; r < 4; ++r) {
            int row = m0 + lh * 4 + r;
            int b72 = (row >> 7) * 72;
            float s0 = 1.f / (1.f + expf(-(acc0[r] + rowbias[b72 + 48 + l16])));
            float s1 = -1e30f;
            if (l16 < 8)
                s1 = 1.f / (1.f + expf(-(acc1[r] + rowbias[b72 + 64 + l16])));
            float mx = fmaxf(s0, s1);
#pragma unroll
            for (int s = 1; s < 16; s <<= 1)
                mx = fmaxf(mx, __shfl_xor(mx, s));
            float e0 = expf(s0 - mx);
            float e1 = (l16 < 8) ? expf(s1 - mx) : 0.f;
            float sum = e0 + e1;
#pragma unroll
            for (int s = 1; s < 16; s <<= 1)
                sum += __shfl_xor(sum, s);
            attn[row * 24 + l16] = e0 / sum;
            if (l16 < 8) attn[row * 24 + 16 + l16] = e1 / sum;
        }
    }
}

// bilinear gather + attn-weighted mean over 24 keypoints
__global__ __launch_bounds__(128) void r2d_k(
    const float* __restrict__ v, const float* __restrict__ lx,
    const float* __restrict__ ly, const float* __restrict__ attn,
    float* __restrict__ r2d)
{
    int n = blockIdx.x;
    int b = blockIdx.y;
    int c = threadIdx.x;
    int row = b * 128 + n;
    __shared__ float sx[24], sy[24], sa[24];
    if (c < 24) { sx[c] = lx[row * 24 + c]; sy[c] = ly[row * 24 + c]; sa[c] = attn[row * 24 + c]; }
    __syncthreads();
    const float* vb = v + (long)b * 512 * 128;
    float acc = 0.f;
    for (int k = 0; k < 24; ++k) {
        float lxv = sx[k], lyv = sy[k], a = sa[k];
        float x1 = floorf(lxv * 15.f), x2 = fminf(x1 + 1.f, 15.f);
        float y1 = floorf(lyv * 31.f), y2 = fminf(y1 + 1.f, 31.f);
        int xi1 = (int)x1, xi2 = (int)x2, yi1 = (int)y1, yi2 = (int)y2;
        float f0 = vb[(xi1 * 16 + yi2) * 128 + c];
        float f1 = vb[(xi2 * 16 + yi2) * 128 + c];
        float f2 = vb[(xi2 * 16 + yi1) * 128 + c];
        float f3 = vb[(xi1 * 16 + yi1) * 128 + c];
        float x = lxv * 16.f, y = lyv * 32.f;
        float w_ = x2 - x1, h_ = y2 - y1;
        float hwp = h_ * w_;
        bool deg = (h_ == 0.f) || (w_ == 0.f);
        float denom = (hwp == 0.f) ? 1.f : hwp;
        float coeff = deg ? 2.f : 1.f / denom;
        float xv0 = (w_ == 0.f) ? 1.f : (x2 - x);
        float xv1 = (w_ == 0.f) ? 1.f : (x - x1);
        float yv0 = (h_ == 0.f) ? 1.f : (y2 - y);
        float yv1 = (h_ == 0.f) ? 1.f : (y - y1);
        float interp = coeff * (xv0 * (f0 * yv0 + f1 * yv1) + xv1 * (f2 * yv0 + f3 * yv1));
        acc = fmaf(interp, a, acc);
    }
    r2d[(long)row * 128 + c] = acc * (1.f / 24.f);
}

// final_embedding[b,c] = mean over n of r2d
__global__ __launch_bounds__(128) void fe_k(const float* __restrict__ r2d,
                                            float* __restrict__ fe)
{
    int b = blockIdx.x;
    int c = threadIdx.x;
    float acc = 0.f;
    for (int nn = 0; nn < 128; ++nn) acc += r2d[((long)b * 128 + nn) * 128 + c];
    fe[b * 128 + c] = acc * (1.f / 128.f);
}

// cls_score = fe @ W_cls, thread-per-output
__global__ __launch_bounds__(256) void cls_k(
    const float* __restrict__ fe, const float* __restrict__ W_cls,
    float* __restrict__ out)
{
    int idx = blockIdx.x * 256 + threadIdx.x;
    if (idx >= 64 * 751) return;
    int m = idx / 751, n = idx - m * 751;
    const float* fr = fe + m * 128;
    float acc = 0.f;
    for (int k = 0; k < 128; ++k)
        acc = fmaf(fr[k], W_cls[k * 751 + n], acc);
    out[idx] = acc;
}

extern "C" void kernel_launch(void* const* d_in, const int* in_sizes, int n_in,
                              void* d_out, int out_size, void* d_ws, size_t ws_size,
                              hipStream_t stream)
{
    const float* features = (const float*)d_in[0];
    const float* d        = (const float*)d_in[1];
    const float* W_rg  = (const float*)d_in[2];
    const float* b_rg  = (const float*)d_in[3];
    const float* W_rl  = (const float*)d_in[4];
    const float* b_rl  = (const float*)d_in[5];
    const float* c1w   = (const float*)d_in[6];
    const float* c1b   = (const float*)d_in[7];
    const float* c2w   = (const float*)d_in[8];
    const float* c2b   = (const float*)d_in[9];
    const float* c3w   = (const float*)d_in[10];
    const float* c3b   = (const float*)d_in[11];
    const float* g_depth = (const float*)d_in[12];
    const float* W_merge = (const float*)d_in[13];
    const float* b_merge = (const float*)d_in[14];
    const float* W_q   = (const float*)d_in[15];
    const float* b_q   = (const float*)d_in[16];
    const float* W_v   = (const float*)d_in[17];
    const float* b_v   = (const float*)d_in[18];
    const float* W_sel = (const float*)d_in[19];
    const float* b_sel = (const float*)d_in[20];
    const float* W_cls = (const float*)d_in[21];
    float* out = (float*)d_out;

    char* ws = (char*)d_ws;
    __hip_bfloat16* c1 = (__hip_bfloat16*)(ws + 0);            // NHWC, ws[0 .. 67,108,864)
    float* dep    = (float*)(ws + 0);                          // 16,777,216 (c1 dead after conv2)
    float* v      = (float*)(ws + 33554432);                   // 16,777,216
    __hip_bfloat16* c2 = (__hip_bfloat16*)(ws + 67108864);     // NHWC 33,554,432
    __hip_bfloat16* w2t = (__hip_bfloat16*)(ws + 100663296);          // 147,456
    __hip_bfloat16* w3t = (__hip_bfloat16*)(ws + 100810752);          // 294,912
    // folded-weight buffers: dead gap, untouched by convs
    float* W_qs    = (float*)(ws + 101105664);                 // 73,728
    float* W_mv    = (float*)(ws + 101179392);                 // 65,536
    float* W_big   = (float*)(ws + 101244928);                 // 221,184
    float* rowbias = (float*)(ws + 101466112);                 // 18,432
    float* c0b     = (float*)(ws + 101484544);                 // 512
    float* c0v     = (float*)(ws + 101485056);                 // 512
    float* gfeat   = (float*)(ws + 101485568);                 // 32,768
    __hip_bfloat16* Wmv_bh = (__hip_bfloat16*)(ws + 101518336);  // 32,768
    __hip_bfloat16* Wmv_bl = (__hip_bfloat16*)(ws + 101551104);  // 32,768
    __hip_bfloat16* Wbig_h = (__hip_bfloat16*)(ws + 101583872);  // 122,880
    __hip_bfloat16* Wbig_l = (__hip_bfloat16*)(ws + 101706752);  // 122,880 (ends 101,829,632)
    float* lxb    = (float*)(ws + 111411200);                  // 786,432
    float* lyb    = (float*)(ws + 112197632);                  // 786,432
    float* attnb  = (float*)(ws + 112984064);                  // 786,432
    float* r2d    = (float*)(ws + 113836544);                  // 4,194,304

    float* fe = out + 64 * 751;

    // ---- prep (folded weights) ----
    prep1_k<<<329, 256, 0, stream>>>(W_q, W_sel, W_merge, W_v, g_depth, b_merge,
                                     features, W_rg, b_rg, W_qs, W_mv, c0b, gfeat);
    prep2_k<<<289, 256, 0, stream>>>(W_rl, W_qs, W_sel, b_rl, b_q, b_sel,
                                     gfeat, c0b, W_v, b_v, W_big, rowbias, c0v);
    prep3_k<<<64, 256, 0, stream>>>(W_mv, Wmv_bh, Wmv_bl);
    prep4_k<<<240, 256, 0, stream>>>(W_big, Wbig_h, Wbig_l);
    wt2_k<<<288, 256, 0, stream>>>(c2w, w2t);
    wt3_k<<<576, 256, 0, stream>>>(c3w, w3t);

    // ---- conv path (MFMA) ----
    conv1_k<<<16384, 256, 0, stream>>>(d, c1w, c1b, c1);
    conv2_mfma<<<dim3(32, 64), 256, 0, stream>>>(c1, w2t, c2b, c2);
    conv3_mfma<<<dim3(8, 64), 256, 0, stream>>>(c2, w3t, c3b, dep);

    // v = dep @ W_mv + c0v   (MFMA hi/lo)
    vgemm_mfma<<<512, 256, 0, stream>>>(dep, Wmv_bh, Wmv_bl, c0v, v);
    // sel (MFMA hi/lo GEMM + sigmoid + softmax fused)
    selmfma_k<<<512, 256, 0, stream>>>(features, Wbig_h, Wbig_l, rowbias,
                                       lxb, lyb, attnb);

    // ---- fusion tail ----
    r2d_k<<<dim3(128, 64), 128, 0, stream>>>(v, lxb, lyb, attnb, r2d);
    fe_k<<<64, 128, 0, stream>>>(r2d, fe);
    cls_k<<<188, 256, 0, stream>>>(fe, W_cls, out);
}

// Round 11
// 225.411 us; speedup vs baseline: 1.5874x; 1.0786x over previous
//
#include <hip/hip_runtime.h>
#include <hip/hip_bf16.h>

// ---------------------------------------------------------------------------
// FourDNet forward. Convs = bf16 MFMA implicit GEMM (NHWC). Folded chain:
//   v   = dep @ (W_merge_bot @ W_v) + c0v            [MFMA hi/lo split]
//   sel = sigmoid(F[:,1:] @ W_big + rowbias[b])      [MFMA hi/lo + fused softmax]
// WS rule (round 4): prep/folded buffers live outside ws[0..64MB] (c1 region).
// Round 11: r10 showed bank conflicts NOT critical (pad changed counter 2x,
//   time flat). conv2/3 cost = 36/72 barrier-pairs with 8 MFMA/wave each.
//   Now: full-k-per-s staging -> 18 barriers, 32 MFMA/wave per pair, LDS
//   37KB (conv2) / 52KB (conv3), stride 36/68 dwords (==4 mod 32, <=2-way).
// ---------------------------------------------------------------------------

typedef __attribute__((ext_vector_type(8))) short short8;
typedef __attribute__((ext_vector_type(4))) short shortx4;
typedef __attribute__((ext_vector_type(4))) float floatx4;

#define MFMA16(a, b, c) __builtin_amdgcn_mfma_f32_16x16x32_bf16(a, b, c, 0, 0, 0)

// ---- prep1: W_qs [256][72], W_mv [128][128], c0 [128], gfeat [64][128] ----
__global__ __launch_bounds__(256) void prep1_k(
    const float* __restrict__ W_q, const float* __restrict__ W_sel,
    const float* __restrict__ W_merge, const float* __restrict__ W_v,
    const float* __restrict__ g_depth, const float* __restrict__ b_merge,
    const float* __restrict__ features, const float* __restrict__ W_rg,
    const float* __restrict__ b_rg,
    float* __restrict__ W_qs, float* __restrict__ W_mv,
    float* __restrict__ c0, float* __restrict__ gfeat)
{
    __shared__ float fr_s[768];
    int bid = blockIdx.x, t = threadIdx.x;
    if (bid < 72) {
        int j = bid;
        float acc = 0.f;
        for (int k = 0; k < 128; ++k)
            acc = fmaf(W_q[t * 128 + k], W_sel[k * 72 + j], acc);
        W_qs[t * 72 + j] = acc;
    } else if (bid < 200) {
        int j = bid - 72;
        if (t < 128) {
            float acc = 0.f;
            for (int k = 0; k < 128; ++k)
                acc = fmaf(W_merge[(128 + t) * 128 + k], W_v[k * 128 + j], acc);
            W_mv[t * 128 + j] = acc;
        }
    } else if (bid == 200) {
        if (t < 128) {
            float acc = b_merge[t];
            for (int k = 0; k < 128; ++k)
                acc = fmaf(g_depth[k], W_merge[k * 128 + t], acc);
            c0[t] = acc;
        }
    } else {                              // gfeat row = bid-201 (64 rows)
        int row = bid - 201;
        for (int l = t; l < 768; l += 256)
            fr_s[l] = features[(long)row * 129 * 768 + l];
        __syncthreads();
        if (t < 128) {
            float acc = b_rg[t];
            for (int k = 0; k < 768; ++k)
                acc = fmaf(fr_s[k], W_rg[k * 128 + t], acc);
            gfeat[row * 128 + t] = acc;
        }
    }
}

// ---- prep2: W_big [768][72], rowbias [64][72], c0v [128] ----
__global__ __launch_bounds__(256) void prep2_k(
    const float* __restrict__ W_rl, const float* __restrict__ W_qs,
    const float* __restrict__ W_sel, const float* __restrict__ b_rl,
    const float* __restrict__ b_q, const float* __restrict__ b_sel,
    const float* __restrict__ gfeat, const float* __restrict__ c0,
    const float* __restrict__ W_v, const float* __restrict__ b_v,
    float* __restrict__ W_big, float* __restrict__ rowbias,
    float* __restrict__ c0v)
{
    int bid = blockIdx.x, t = threadIdx.x;
    if (bid < 216) {
        int j = bid / 3;
        int i = (bid % 3) * 256 + t;
        float acc = 0.f;
        for (int k = 0; k < 128; ++k)
            acc = fmaf(W_rl[i * 128 + k], W_qs[(128 + k) * 72 + j], acc);
        W_big[i * 72 + j] = acc;
    } else if (bid < 288) {
        int j = bid - 216;
        if (t < 64) {
            float vb = b_sel[j];
            for (int k = 0; k < 128; ++k) {
                vb = fmaf(b_rl[k], W_qs[(128 + k) * 72 + j], vb);
                vb = fmaf(b_q[k], W_sel[k * 72 + j], vb);
            }
            float acc = vb;
            for (int k = 0; k < 128; ++k)
                acc = fmaf(gfeat[t * 128 + k], W_qs[k * 72 + j], acc);
            rowbias[t * 72 + j] = acc;
        }
    } else {
        if (t < 128) {
            float acc = b_v[t];
            for (int k = 0; k < 128; ++k)
                acc = fmaf(c0[k], W_v[k * 128 + t], acc);
            c0v[t] = acc;
        }
    }
}

// ---- prep3: W_mv -> B-transposed bf16 hi/lo [n][k] ----
__global__ __launch_bounds__(256) void prep3_k(
    const float* __restrict__ W_mv,
    __hip_bfloat16* __restrict__ Bh, __hip_bfloat16* __restrict__ Bl)
{
    int idx = blockIdx.x * 256 + threadIdx.x;   // 16384
    int n = idx >> 7, k = idx & 127;
    float w = W_mv[k * 128 + n];
    __hip_bfloat16 h = __float2bfloat16(w);
    Bh[idx] = h;
    Bl[idx] = __float2bfloat16(w - __bfloat162float(h));
}

// ---- prep4: W_big [768][72] -> bf16 hi/lo [80][768] (n-major, cols>=72 zero)
__global__ __launch_bounds__(256) void prep4_k(
    const float* __restrict__ W_big,
    __hip_bfloat16* __restrict__ Wbh, __hip_bfloat16* __restrict__ Wbl)
{
    int idx = blockIdx.x * 256 + threadIdx.x;   // 80*768 = 61440
    if (idx >= 80 * 768) return;
    int n = idx / 768, k = idx - n * 768;
    float w = (n < 72) ? W_big[k * 72 + n] : 0.f;
    __hip_bfloat16 h = __float2bfloat16(w);
    Wbh[idx] = h;
    Wbl[idx] = __float2bfloat16(w - __bfloat162float(h));
}

// weight transform: OIHW fp32 -> [oc][(kh*3+kw)*IC + ic] bf16
__global__ __launch_bounds__(256) void wt2_k(const float* __restrict__ w,
                                             __hip_bfloat16* __restrict__ wt)
{
    int idx = blockIdx.x * 256 + threadIdx.x;
    if (idx >= 128 * 576) return;
    int oc = idx / 576, k = idx % 576;
    int s = k >> 6, ic = k & 63;
    wt[idx] = __float2bfloat16(w[oc * 576 + ic * 9 + s]);
}
__global__ __launch_bounds__(256) void wt3_k(const float* __restrict__ w,
                                             __hip_bfloat16* __restrict__ wt)
{
    int idx = blockIdx.x * 256 + threadIdx.x;
    if (idx >= 128 * 1152) return;
    int oc = idx / 1152, k = idx % 1152;
    int s = k >> 7, ic = k & 127;
    wt[idx] = __float2bfloat16(w[oc * 1152 + ic * 9 + s]);
}

// conv1: d (64,1,256,128) f32 -> out NHWC (64,128,64,64) bf16. stride2 pad1.
__global__ __launch_bounds__(256) void conv1_k(
    const float* __restrict__ d, const float* __restrict__ w,
    const float* __restrict__ bias, __hip_bfloat16* __restrict__ out)
{
    __shared__ float in_s[3][66];
    __shared__ float ws_[576];
    __shared__ float bs_[64];
    int tid = threadIdx.x;
    int owhalf = blockIdx.x & 1;
    int oh = (blockIdx.x >> 1) & 127;
    int b  = blockIdx.x >> 8;
    int owbase = owhalf * 32;

    for (int l = tid; l < 576; l += 256) ws_[l] = w[l];
    if (tid < 64) bs_[tid] = bias[tid];
    for (int l = tid; l < 3 * 66; l += 256) {
        int r = l / 66, c = l % 66;
        int ih = 2 * oh - 1 + r;
        int iw = 2 * owbase - 1 + c;
        float v = 0.f;
        if ((unsigned)ih < 256u && (unsigned)iw < 128u)
            v = d[(b * 256 + ih) * 128 + iw];
        in_s[r][c] = v;
    }
    __syncthreads();

    int owl = tid >> 3, ocg = tid & 7;
    float in9[9];
#pragma unroll
    for (int r = 0; r < 3; ++r)
#pragma unroll
        for (int c = 0; c < 3; ++c)
            in9[r * 3 + c] = in_s[r][2 * owl + c];

    short8 res;
#pragma unroll
    for (int j = 0; j < 8; ++j) {
        int oc = ocg * 8 + j;
        float a = bs_[oc];
#pragma unroll
        for (int s = 0; s < 9; ++s) a = fmaf(in9[s], ws_[oc * 9 + s], a);
        union { __hip_bfloat16 h; short s; } u;
        u.h = __float2bfloat16(a);
        res[j] = u.s;
    }
    long pos = ((long)(b * 128 + oh) * 64 + owbase + owl);
    *(short8*)((short*)out + pos * 64 + ocg * 8) = res;
}

// conv2 MFMA: in NHWC (64,128,64,64) bf16, w2t [128][576] bf16
//            -> out NHWC (64,64,32,128) bf16
// M-tile 128 (4oh x 32ow), full k=64 staged per s: 18 barriers total.
// LDS stride 72 shorts (36 dwords == 4 mod 32): reads <=2-way conflict.
__global__ __launch_bounds__(256) void conv2_mfma(
    const __hip_bfloat16* __restrict__ in, const __hip_bfloat16* __restrict__ w2t,
    const float* __restrict__ bias, __hip_bfloat16* __restrict__ out)
{
    __shared__ short A_lds[128][72];   // 18,432 B
    __shared__ short B_lds[128][72];   // 18,432 B (36.9 KB total)
    int tid = threadIdx.x;
    int oh0 = blockIdx.x * 4;          // 4 oh x 32 ow = 128 positions
    int b   = blockIdx.y;
    int lane = tid & 63, wave = tid >> 6;
    int l16 = lane & 15, lh = lane >> 4;
    const short* inp = (const short*)in;
    const short* w2p = (const short*)w2t;

    floatx4 acc[2][8] = {};

    for (int s = 0; s < 9; ++s) {
        int kh = s / 3, kw = s - kh * 3;
        short8 av[4], bv[4];
#pragma unroll
        for (int i = 0; i < 4; ++i) {   // 1024 chunks: pos/oc = c>>3, seg = c&7
            int c = tid + i * 256;
            int pos = c >> 3, seg = c & 7;
            int ohl = pos >> 5, ow = pos & 31;
            int ih = 2 * (oh0 + ohl) - 1 + kh;
            int iw = 2 * ow - 1 + kw;
            short8 v = {0,0,0,0,0,0,0,0};
            if ((unsigned)ih < 128u && (unsigned)iw < 64u)
                v = *(const short8*)(inp + (((long)(b * 128 + ih) * 64 + iw) * 64 + seg * 8));
            av[i] = v;
            bv[i] = *(const short8*)(w2p + pos * 576 + s * 64 + seg * 8);
        }
        __syncthreads();               // previous step's LDS reads complete
#pragma unroll
        for (int i = 0; i < 4; ++i) {
            int c = tid + i * 256;
            int pos = c >> 3, seg = c & 7;
            *(short8*)&A_lds[pos][seg * 8] = av[i];
            *(short8*)&B_lds[pos][seg * 8] = bv[i];
        }
        __syncthreads();
#pragma unroll
        for (int half = 0; half < 2; ++half) {
            short8 a0 = *(const short8*)&A_lds[wave * 32 + l16][half * 32 + lh * 8];
            short8 a1 = *(const short8*)&A_lds[wave * 32 + 16 + l16][half * 32 + lh * 8];
#pragma unroll
            for (int ni = 0; ni < 8; ++ni) {
                short8 bvf = *(const short8*)&B_lds[ni * 16 + l16][half * 32 + lh * 8];
                acc[0][ni] = MFMA16(a0, bvf, acc[0][ni]);
                acc[1][ni] = MFMA16(a1, bvf, acc[1][ni]);
            }
        }
    }

    float bf[8];
#pragma unroll
    for (int ni = 0; ni < 8; ++ni) bf[ni] = bias[ni * 16 + l16];
#pragma unroll
    for (int mi = 0; mi < 2; ++mi)
#pragma unroll
        for (int r = 0; r < 4; ++r) {
            int m = wave * 32 + mi * 16 + lh * 4 + r;
            int ohl = m >> 5, ow = m & 31;
            __hip_bfloat16* op = out + (((long)(b * 64 + oh0 + ohl) * 32) + ow) * 128;
#pragma unroll
            for (int ni = 0; ni < 8; ++ni) {
                int oc = ni * 16 + l16;
                op[oc] = __float2bfloat16(acc[mi][ni][r] + bf[ni]);
            }
        }
}

// conv3 MFMA: in NHWC (64,64,32,128) bf16, w3t [128][1152] bf16
//            -> dep (64*512, 128) fp32
// M-tile 64 (4oh x 16ow), full k=128 staged per s: 18 barriers total.
__global__ __launch_bounds__(256) void conv3_mfma(
    const __hip_bfloat16* __restrict__ in, const __hip_bfloat16* __restrict__ w3t,
    const float* __restrict__ bias, float* __restrict__ dep)
{
    __shared__ short A_lds[64][136];   // 17,408 B
    __shared__ short B_lds[128][136];  // 34,816 B (52.2 KB total)
    int tid = threadIdx.x;
    int oh0 = blockIdx.x * 4;          // 4 oh x 16 ow = 64 positions
    int b   = blockIdx.y;
    int lane = tid & 63, wave = tid >> 6;
    int wr = wave >> 1, wc = wave & 1;
    int l16 = lane & 15, lh = lane >> 4;
    const short* inp = (const short*)in;
    const short* w3p = (const short*)w3t;

    floatx4 acc[2][4] = {};

    for (int s = 0; s < 9; ++s) {
        int kh = s / 3, kw = s - kh * 3;
        short8 av[4], bv[8];
#pragma unroll
        for (int i = 0; i < 4; ++i) {   // A: 1024 chunks: pos = c>>4, seg = c&15
            int c = tid + i * 256;
            int pos = c >> 4, seg = c & 15;
            int oa = pos >> 4, ow = pos & 15;
            int ih = 2 * (oh0 + oa) - 1 + kh;
            int iw = 2 * ow - 1 + kw;
            short8 v = {0,0,0,0,0,0,0,0};
            if ((unsigned)ih < 64u && (unsigned)iw < 32u)
                v = *(const short8*)(inp + (((long)(b * 64 + ih) * 32 + iw) * 128 + seg * 8));
            av[i] = v;
        }
#pragma unroll
        for (int i = 0; i < 8; ++i) {   // B: 2048 chunks: oc = c>>4, seg = c&15
            int c = tid + i * 256;
            int oc = c >> 4, seg = c & 15;
            bv[i] = *(const short8*)(w3p + oc * 1152 + s * 128 + seg * 8);
        }
        __syncthreads();
#pragma unroll
        for (int i = 0; i < 4; ++i) {
            int c = tid + i * 256;
            int pos = c >> 4, seg = c & 15;
            *(short8*)&A_lds[pos][seg * 8] = av[i];
        }
#pragma unroll
        for (int i = 0; i < 8; ++i) {
            int c = tid + i * 256;
            int oc = c >> 4, seg = c & 15;
            *(short8*)&B_lds[oc][seg * 8] = bv[i];
        }
        __syncthreads();
#pragma unroll
        for (int ks = 0; ks < 4; ++ks) {
            short8 a0 = *(const short8*)&A_lds[wr * 32 + l16][ks * 32 + lh * 8];
            short8 a1 = *(const short8*)&A_lds[wr * 32 + 16 + l16][ks * 32 + lh * 8];
#pragma unroll
            for (int ni = 0; ni < 4; ++ni) {
                short8 bvf = *(const short8*)&B_lds[wc * 64 + ni * 16 + l16][ks * 32 + lh * 8];
                acc[0][ni] = MFMA16(a0, bvf, acc[0][ni]);
                acc[1][ni] = MFMA16(a1, bvf, acc[1][ni]);
            }
        }
    }

    float bf[4];
#pragma unroll
    for (int ni = 0; ni < 4; ++ni) bf[ni] = bias[wc * 64 + ni * 16 + l16];
#pragma unroll
    for (int mi = 0; mi < 2; ++mi)
#pragma unroll
        for (int r = 0; r < 4; ++r) {
            int m = wr * 32 + mi * 16 + lh * 4 + r;
            int oa2 = m >> 4, ow2 = m & 15;
            float* op = dep + ((long)b * 512 + (oh0 + oa2) * 16 + ow2) * 128;
#pragma unroll
            for (int ni = 0; ni < 4; ++ni) {
                int oc = wc * 64 + ni * 16 + l16;
                op[oc] = acc[mi][ni][r] + bf[ni];
            }
        }
}

// v = dep @ W_mv + c0v via bf16 MFMA hi/lo split (~fp32 accuracy).
__global__ __launch_bounds__(256) void vgemm_mfma(
    const float* __restrict__ dep, const __hip_bfloat16* __restrict__ Bh,
    const __hip_bfloat16* __restrict__ Bl, const float* __restrict__ c0v,
    float* __restrict__ v)
{
    __shared__ short Ah[64][136];
    __shared__ short Al[64][136];
    int tid = threadIdx.x;
    int m0 = blockIdx.x * 64;

    for (int l4 = tid; l4 < 64 * 32; l4 += 256) {
        int r = l4 >> 5, c4 = l4 & 31;
        const float* sp = dep + ((long)(m0 + r) << 7) + c4 * 4;
        shortx4 hv, lv;
#pragma unroll
        for (int i = 0; i < 4; ++i) {
            float f = sp[i];
            union { __hip_bfloat16 b; short s; } uh, ul;
            uh.b = __float2bfloat16(f);
            ul.b = __float2bfloat16(f - __bfloat162float(uh.b));
            hv[i] = uh.s; lv[i] = ul.s;
        }
        *(shortx4*)&Ah[r][c4 * 4] = hv;
        *(shortx4*)&Al[r][c4 * 4] = lv;
    }
    __syncthreads();

    int lane = tid & 63, wave = tid >> 6;
    int wr = wave >> 1, wc = wave & 1;
    int l16 = lane & 15, lh = lane >> 4;
    floatx4 acc[2][4] = {};
#pragma unroll
    for (int kk = 0; kk < 4; ++kk) {
        short8 ah[2], al[2];
#pragma unroll
        for (int mi = 0; mi < 2; ++mi) {
            ah[mi] = *(const short8*)&Ah[wr * 32 + mi * 16 + l16][kk * 32 + lh * 8];
            al[mi] = *(const short8*)&Al[wr * 32 + mi * 16 + l16][kk * 32 + lh * 8];
        }
#pragma unroll
        for (int nf = 0; nf < 4; ++nf) {
            int gn = wc * 64 + nf * 16 + l16;
            short8 bh = *(const short8*)((const short*)Bh + gn * 128 + kk * 32 + lh * 8);
            short8 bl = *(const short8*)((const short*)Bl + gn * 128 + kk * 32 + lh * 8);
#pragma unroll
            for (int mi = 0; mi < 2; ++mi) {
                acc[mi][nf] = MFMA16(ah[mi], bh, acc[mi][nf]);
                acc[mi][nf] = MFMA16(al[mi], bh, acc[mi][nf]);
                acc[mi][nf] = MFMA16(ah[mi], bl, acc[mi][nf]);
            }
        }
    }
#pragma unroll
    for (int nf = 0; nf < 4; ++nf) {
        int gn = wc * 64 + nf * 16 + l16;
        float cv = c0v[gn];
#pragma unroll
        for (int mi = 0; mi < 2; ++mi)
#pragma unroll
            for (int r = 0; r < 4; ++r) {
                int m = m0 + wr * 32 + mi * 16 + lh * 4 + r;
                v[(long)m * 128 + gn] = acc[mi][nf][r] + cv;
            }
    }
}

// sel: MFMA hi/lo GEMM (8192 x 80pad x 768) + fused sigmoid + softmax.
__global__ __launch_bounds__(256) void selmfma_k(
    const float* __restrict__ F, const __hip_bfloat16* __restrict__ Wbh,
    const __hip_bfloat16* __restrict__ Wbl, const float* __restrict__ rowbias,
    float* __restrict__ lx, float* __restrict__ ly, float* __restrict__ attn)
{
    __shared__ short Ah[16][136];
    __shared__ short Al[16][136];
    int tid = threadIdx.x;
    int m0 = blockIdx.x * 16;
    int padd = (m0 >> 7) + 1;
    int lane = tid & 63, wave = tid >> 6;
    int l16 = lane & 15, lh = lane >> 4;

    int sr = tid >> 4, sc = (tid & 15) * 8;
    const float* fsrc = F + (long)(m0 + sr + padd) * 768 + sc;

    floatx4 acc0 = {0.f, 0.f, 0.f, 0.f};
    floatx4 acc1 = {0.f, 0.f, 0.f, 0.f};
    bool two = (wave == 3);
    const short* bhp = (const short*)Wbh;
    const short* blp = (const short*)Wbl;
    int gn0 = wave * 16 + l16;
    int gn1 = 64 + l16;

    for (int c = 0; c < 6; ++c) {
        __syncthreads();
        float4 f0 = *(const float4*)(fsrc + c * 128);
        float4 f1 = *(const float4*)(fsrc + c * 128 + 4);
        shortx4 h0, l0, h1, l1;
#pragma unroll
        for (int i = 0; i < 4; ++i) {
            union { __hip_bfloat16 b; short s; } uh, ul;
            float fa = (&f0.x)[i];
            uh.b = __float2bfloat16(fa);
            ul.b = __float2bfloat16(fa - __bfloat162float(uh.b));
            h0[i] = uh.s; l0[i] = ul.s;
            float fb = (&f1.x)[i];
            uh.b = __float2bfloat16(fb);
            ul.b = __float2bfloat16(fb - __bfloat162float(uh.b));
            h1[i] = uh.s; l1[i] = ul.s;
        }
        *(shortx4*)&Ah[sr][sc]     = h0;
        *(shortx4*)&Ah[sr][sc + 4] = h1;
        *(shortx4*)&Al[sr][sc]     = l0;
        *(shortx4*)&Al[sr][sc + 4] = l1;
        __syncthreads();
#pragma unroll
        for (int ks = 0; ks < 4; ++ks) {
            short8 ah = *(const short8*)&Ah[l16][ks * 32 + lh * 8];
            short8 al = *(const short8*)&Al[l16][ks * 32 + lh * 8];
            int koff = c * 128 + ks * 32 + lh * 8;
            short8 bh0 = *(const short8*)(bhp + gn0 * 768 + koff);
            short8 bl0 = *(const short8*)(blp + gn0 * 768 + koff);
            acc0 = MFMA16(ah, bh0, acc0);
            acc0 = MFMA16(al, bh0, acc0);
            acc0 = MFMA16(ah, bl0, acc0);
            if (two) {
                short8 bh1 = *(const short8*)(bhp + gn1 * 768 + koff);
                short8 bl1 = *(const short8*)(blp + gn1 * 768 + koff);
                acc1 = MFMA16(ah, bh1, acc1);
                acc1 = MFMA16(al, bh1, acc1);
                acc1 = MFMA16(ah, bl1, acc1);
            }
        }
    }

    if (wave < 3) {
        int j = wave * 16 + l16;
#pragma unroll
        for (int r = 0; r < 4; ++r) {
            int row = m0 + lh * 4 + r;
            float val = acc0[r] + rowbias[(row >> 7) * 72 + j];
            float sg = 1.f / (1.f + expf(-val));
            if (j & 1) ly[row * 24 + (j >> 1)] = sg;
            else       lx[row * 24 + (j >> 1)] = sg;
        }
    } else {
#pragma unroll
        for (int r = 0; r < 4; ++r) {
            int row = m0 + lh * 4 + r;
            int b72 = (row >> 7) * 72;
            float s0 = 1.f / (1.f + expf(-(acc0[r] + rowbias[b72 + 48 + l16])));
            float s1 = -1e30f;
            if (l16 < 8)
                s1 = 1.f / (1.f + expf(-(acc1[r] + rowbias[b72 + 64 + l16])));
            float mx = fmaxf(s0, s1);
#pragma unroll
            for (int s = 1; s < 16; s <<= 1)
                mx = fmaxf(mx, __shfl_xor(mx, s));
            float e0 = expf(s0 - mx);
            float e1 = (l16 < 8) ? expf(s1 - mx) : 0.f;
            float sum = e0 + e1;
#pragma unroll
            for (int s = 1; s < 16; s <<= 1)
                sum += __shfl_xor(sum, s);
            attn[row * 24 + l16] = e0 / sum;
            if (l16 < 8) attn[row * 24 + 16 + l16] = e1 / sum;
        }
    }
}

// bilinear gather + attn-weighted mean over 24 keypoints
__global__ __launch_bounds__(128) void r2d_k(
    const float* __restrict__ v, const float* __restrict__ lx,
    const float* __restrict__ ly, const float* __restrict__ attn,
    float* __restrict__ r2d)
{
    int n = blockIdx.x;
    int b = blockIdx.y;
    int c = threadIdx.x;
    int row = b * 128 + n;
    __shared__ float sx[24], sy[24], sa[24];
    if (c < 24) { sx[c] = lx[row * 24 + c]; sy[c] = ly[row * 24 + c]; sa[c] = attn[row * 24 + c]; }
    __syncthreads();
    const float* vb = v + (long)b * 512 * 128;
    float acc = 0.f;
    for (int k = 0; k < 24; ++k) {
        float lxv = sx[k], lyv = sy[k], a = sa[k];
        float x1 = floorf(lxv * 15.f), x2 = fminf(x1 + 1.f, 15.f);
        float y1 = floorf(lyv * 31.f), y2 = fminf(y1 + 1.f, 31.f);
        int xi1 = (int)x1, xi2 = (int)x2, yi1 = (int)y1, yi2 = (int)y2;
        float f0 = vb[(xi1 * 16 + yi2) * 128 + c];
        float f1 = vb[(xi2 * 16 + yi2) * 128 + c];
        float f2 = vb[(xi2 * 16 + yi1) * 128 + c];
        float f3 = vb[(xi1 * 16 + yi1) * 128 + c];
        float x = lxv * 16.f, y = lyv * 32.f;
        float w_ = x2 - x1, h_ = y2 - y1;
        float hwp = h_ * w_;
        bool deg = (h_ == 0.f) || (w_ == 0.f);
        float denom = (hwp == 0.f) ? 1.f : hwp;
        float coeff = deg ? 2.f : 1.f / denom;
        float xv0 = (w_ == 0.f) ? 1.f : (x2 - x);
        float xv1 = (w_ == 0.f) ? 1.f : (x - x1);
        float yv0 = (h_ == 0.f) ? 1.f : (y2 - y);
        float yv1 = (h_ == 0.f) ? 1.f : (y - y1);
        float interp = coeff * (xv0 * (f0 * yv0 + f1 * yv1) + xv1 * (f2 * yv0 + f3 * yv1));
        acc = fmaf(interp, a, acc);
    }
    r2d[(long)row * 128 + c] = acc * (1.f / 24.f);
}

// final_embedding[b,c] = mean over n of r2d
__global__ __launch_bounds__(128) void fe_k(const float* __restrict__ r2d,
                                            float* __restrict__ fe)
{
    int b = blockIdx.x;
    int c = threadIdx.x;
    float acc = 0.f;
    for (int nn = 0; nn < 128; ++nn) acc += r2d[((long)b * 128 + nn) * 128 + c];
    fe[b * 128 + c] = acc * (1.f / 128.f);
}

// cls_score = fe @ W_cls, thread-per-output
__global__ __launch_bounds__(256) void cls_k(
    const float* __restrict__ fe, const float* __restrict__ W_cls,
    float* __restrict__ out)
{
    int idx = blockIdx.x * 256 + threadIdx.x;
    if (idx >= 64 * 751) return;
    int m = idx / 751, n = idx - m * 751;
    const float* fr = fe + m * 128;
    float acc = 0.f;
    for (int k = 0; k < 128; ++k)
        acc = fmaf(fr[k], W_cls[k * 751 + n], acc);
    out[idx] = acc;
}

extern "C" void kernel_launch(void* const* d_in, const int* in_sizes, int n_in,
                              void* d_out, int out_size, void* d_ws, size_t ws_size,
                              hipStream_t stream)
{
    const float* features = (const float*)d_in[0];
    const float* d        = (const float*)d_in[1];
    const float* W_rg  = (const float*)d_in[2];
    const float* b_rg  = (const float*)d_in[3];
    const float* W_rl  = (const float*)d_in[4];
    const float* b_rl  = (const float*)d_in[5];
    const float* c1w   = (const float*)d_in[6];
    const float* c1b   = (const float*)d_in[7];
    const float* c2w   = (const float*)d_in[8];
    const float* c2b   = (const float*)d_in[9];
    const float* c3w   = (const float*)d_in[10];
    const float* c3b   = (const float*)d_in[11];
    const float* g_depth = (const float*)d_in[12];
    const float* W_merge = (const float*)d_in[13];
    const float* b_merge = (const float*)d_in[14];
    const float* W_q   = (const float*)d_in[15];
    const float* b_q   = (const float*)d_in[16];
    const float* W_v   = (const float*)d_in[17];
    const float* b_v   = (const float*)d_in[18];
    const float* W_sel = (const float*)d_in[19];
    const float* b_sel = (const float*)d_in[20];
    const float* W_cls = (const float*)d_in[21];
    float* out = (float*)d_out;

    char* ws = (char*)d_ws;
    __hip_bfloat16* c1 = (__hip_bfloat16*)(ws + 0);            // NHWC, ws[0 .. 67,108,864)
    float* dep    = (float*)(ws + 0);                          // 16,777,216 (c1 dead after conv2)
    float* v      = (float*)(ws + 33554432);                   // 16,777,216
    __hip_bfloat16* c2 = (__hip_bfloat16*)(ws + 67108864);     // NHWC 33,554,432
    __hip_bfloat16* w2t = (__hip_bfloat16*)(ws + 100663296);          // 147,456
    __hip_bfloat16* w3t = (__hip_bfloat16*)(ws + 100810752);          // 294,912
    // folded-weight buffers: dead gap, untouched by convs
    float* W_qs    = (float*)(ws + 101105664);                 // 73,728
    float* W_mv    = (float*)(ws + 101179392);                 // 65,536
    float* W_big   = (float*)(ws + 101244928);                 // 221,184
    float* rowbias = (float*)(ws + 101466112);                 // 18,432
    float* c0b     = (float*)(ws + 101484544);                 // 512
    float* c0v     = (float*)(ws + 101485056);                 // 512
    float* gfeat   = (float*)(ws + 101485568);                 // 32,768
    __hip_bfloat16* Wmv_bh = (__hip_bfloat16*)(ws + 101518336);  // 32,768
    __hip_bfloat16* Wmv_bl = (__hip_bfloat16*)(ws + 101551104);  // 32,768
    __hip_bfloat16* Wbig_h = (__hip_bfloat16*)(ws + 101583872);  // 122,880
    __hip_bfloat16* Wbig_l = (__hip_bfloat16*)(ws + 101706752);  // 122,880 (ends 101,829,632)
    float* lxb    = (float*)(ws + 111411200);                  // 786,432
    float* lyb    = (float*)(ws + 112197632);                  // 786,432
    float* attnb  = (float*)(ws + 112984064);                  // 786,432
    float* r2d    = (float*)(ws + 113836544);                  // 4,194,304

    float* fe = out + 64 * 751;

    // ---- prep (folded weights) ----
    prep1_k<<<265, 256, 0, stream>>>(W_q, W_sel, W_merge, W_v, g_depth, b_merge,
                                     features, W_rg, b_rg, W_qs, W_mv, c0b, gfeat);
    prep2_k<<<289, 256, 0, stream>>>(W_rl, W_qs, W_sel, b_rl, b_q, b_sel,
                                     gfeat, c0b, W_v, b_v, W_big, rowbias, c0v);
    prep3_k<<<64, 256, 0, stream>>>(W_mv, Wmv_bh, Wmv_bl);
    prep4_k<<<240, 256, 0, stream>>>(W_big, Wbig_h, Wbig_l);
    wt2_k<<<288, 256, 0, stream>>>(c2w, w2t);
    wt3_k<<<576, 256, 0, stream>>>(c3w, w3t);

    // ---- conv path (MFMA) ----
    conv1_k<<<16384, 256, 0, stream>>>(d, c1w, c1b, c1);
    conv2_mfma<<<dim3(16, 64), 256, 0, stream>>>(c1, w2t, c2b, c2);
    conv3_mfma<<<dim3(8, 64), 256, 0, stream>>>(c2, w3t, c3b, dep);

    // v = dep @ W_mv + c0v   (MFMA hi/lo)
    vgemm_mfma<<<512, 256, 0, stream>>>(dep, Wmv_bh, Wmv_bl, c0v, v);
    // sel (MFMA hi/lo GEMM + sigmoid + softmax fused)
    selmfma_k<<<512, 256, 0, stream>>>(features, Wbig_h, Wbig_l, rowbias,
                                       lxb, lyb, attnb);

    // ---- fusion tail ----
    r2d_k<<<dim3(128, 64), 128, 0, stream>>>(v, lxb, lyb, attnb, r2d);
    fe_k<<<64, 128, 0, stream>>>(r2d, fe);
    cls_k<<<188, 256, 0, stream>>>(fe, W_cls, out);
}

// Round 13
// 223.622 us; speedup vs baseline: 1.6001x; 1.0080x over previous
//
#include <hip/hip_runtime.h>
#include <hip/hip_bf16.h>

// ---------------------------------------------------------------------------
// FourDNet forward. Convs = bf16 MFMA implicit GEMM (NHWC). Folded chain:
//   v   = dep @ (W_merge_bot @ W_v) + c0v            [MFMA hi/lo split]
//   sel = sigmoid(F[:,1:] @ W_big + rowbias[b])      [MFMA hi/lo + fused softmax]
// WS rule (round 4): prep/folded buffers live outside ws[0..64MB] (c1 region).
// Round 12: r2d was VALU-bound (96% busy) from 128x-redundant bilinear weight
//   math. Now bw_k precomputes per-(row,k) {4 idx, 4 weights} once (6MB ws);
//   r2d_k = 4 coalesced loads + 4 FMAs per k from LDS-broadcast weights.
// ---------------------------------------------------------------------------

typedef __attribute__((ext_vector_type(8))) short short8;
typedef __attribute__((ext_vector_type(4))) short shortx4;
typedef __attribute__((ext_vector_type(4))) float floatx4;

#define MFMA16(a, b, c) __builtin_amdgcn_mfma_f32_16x16x32_bf16(a, b, c, 0, 0, 0)

// ---- prep1: W_qs [256][72], W_mv [128][128], c0 [128], gfeat [64][128] ----
__global__ __launch_bounds__(256) void prep1_k(
    const float* __restrict__ W_q, const float* __restrict__ W_sel,
    const float* __restrict__ W_merge, const float* __restrict__ W_v,
    const float* __restrict__ g_depth, const float* __restrict__ b_merge,
    const float* __restrict__ features, const float* __restrict__ W_rg,
    const float* __restrict__ b_rg,
    float* __restrict__ W_qs, float* __restrict__ W_mv,
    float* __restrict__ c0, float* __restrict__ gfeat)
{
    __shared__ float fr_s[768];
    int bid = blockIdx.x, t = threadIdx.x;
    if (bid < 72) {
        int j = bid;
        float acc = 0.f;
        for (int k = 0; k < 128; ++k)
            acc = fmaf(W_q[t * 128 + k], W_sel[k * 72 + j], acc);
        W_qs[t * 72 + j] = acc;
    } else if (bid < 200) {
        int j = bid - 72;
        if (t < 128) {
            float acc = 0.f;
            for (int k = 0; k < 128; ++k)
                acc = fmaf(W_merge[(128 + t) * 128 + k], W_v[k * 128 + j], acc);
            W_mv[t * 128 + j] = acc;
        }
    } else if (bid == 200) {
        if (t < 128) {
            float acc = b_merge[t];
            for (int k = 0; k < 128; ++k)
                acc = fmaf(g_depth[k], W_merge[k * 128 + t], acc);
            c0[t] = acc;
        }
    } else {                              // gfeat row = bid-201 (64 rows)
        int row = bid - 201;
        for (int l = t; l < 768; l += 256)
            fr_s[l] = features[(long)row * 129 * 768 + l];
        __syncthreads();
        if (t < 128) {
            float acc = b_rg[t];
            for (int k = 0; k < 768; ++k)
                acc = fmaf(fr_s[k], W_rg[k * 128 + t], acc);
            gfeat[row * 128 + t] = acc;
        }
    }
}

// ---- prep2: W_big [768][72], rowbias [64][72], c0v [128] ----
__global__ __launch_bounds__(256) void prep2_k(
    const float* __restrict__ W_rl, const float* __restrict__ W_qs,
    const float* __restrict__ W_sel, const float* __restrict__ b_rl,
    const float* __restrict__ b_q, const float* __restrict__ b_sel,
    const float* __restrict__ gfeat, const float* __restrict__ c0,
    const float* __restrict__ W_v, const float* __restrict__ b_v,
    float* __restrict__ W_big, float* __restrict__ rowbias,
    float* __restrict__ c0v)
{
    int bid = blockIdx.x, t = threadIdx.x;
    if (bid < 216) {
        int j = bid / 3;
        int i = (bid % 3) * 256 + t;
        float acc = 0.f;
        for (int k = 0; k < 128; ++k)
            acc = fmaf(W_rl[i * 128 + k], W_qs[(128 + k) * 72 + j], acc);
        W_big[i * 72 + j] = acc;
    } else if (bid < 288) {
        int j = bid - 216;
        if (t < 64) {
            float vb = b_sel[j];
            for (int k = 0; k < 128; ++k) {
                vb = fmaf(b_rl[k], W_qs[(128 + k) * 72 + j], vb);
                vb = fmaf(b_q[k], W_sel[k * 72 + j], vb);
            }
            float acc = vb;
            for (int k = 0; k < 128; ++k)
                acc = fmaf(gfeat[t * 128 + k], W_qs[k * 72 + j], acc);
            rowbias[t * 72 + j] = acc;
        }
    } else {
        if (t < 128) {
            float acc = b_v[t];
            for (int k = 0; k < 128; ++k)
                acc = fmaf(c0[k], W_v[k * 128 + t], acc);
            c0v[t] = acc;
        }
    }
}

// ---- prep3: W_mv -> B-transposed bf16 hi/lo [n][k] ----
__global__ __launch_bounds__(256) void prep3_k(
    const float* __restrict__ W_mv,
    __hip_bfloat16* __restrict__ Bh, __hip_bfloat16* __restrict__ Bl)
{
    int idx = blockIdx.x * 256 + threadIdx.x;   // 16384
    int n = idx >> 7, k = idx & 127;
    float w = W_mv[k * 128 + n];
    __hip_bfloat16 h = __float2bfloat16(w);
    Bh[idx] = h;
    Bl[idx] = __float2bfloat16(w - __bfloat162float(h));
}

// ---- prep4: W_big [768][72] -> bf16 hi/lo [80][768] (n-major, cols>=72 zero)
__global__ __launch_bounds__(256) void prep4_k(
    const float* __restrict__ W_big,
    __hip_bfloat16* __restrict__ Wbh, __hip_bfloat16* __restrict__ Wbl)
{
    int idx = blockIdx.x * 256 + threadIdx.x;   // 80*768 = 61440
    if (idx >= 80 * 768) return;
    int n = idx / 768, k = idx - n * 768;
    float w = (n < 72) ? W_big[k * 72 + n] : 0.f;
    __hip_bfloat16 h = __float2bfloat16(w);
    Wbh[idx] = h;
    Wbl[idx] = __float2bfloat16(w - __bfloat162float(h));
}

// weight transform: OIHW fp32 -> [oc][(kh*3+kw)*IC + ic] bf16
__global__ __launch_bounds__(256) void wt2_k(const float* __restrict__ w,
                                             __hip_bfloat16* __restrict__ wt)
{
    int idx = blockIdx.x * 256 + threadIdx.x;
    if (idx >= 128 * 576) return;
    int oc = idx / 576, k = idx % 576;
    int s = k >> 6, ic = k & 63;
    wt[idx] = __float2bfloat16(w[oc * 576 + ic * 9 + s]);
}
__global__ __launch_bounds__(256) void wt3_k(const float* __restrict__ w,
                                             __hip_bfloat16* __restrict__ wt)
{
    int idx = blockIdx.x * 256 + threadIdx.x;
    if (idx >= 128 * 1152) return;
    int oc = idx / 1152, k = idx % 1152;
    int s = k >> 7, ic = k & 127;
    wt[idx] = __float2bfloat16(w[oc * 1152 + ic * 9 + s]);
}

// conv1: d (64,1,256,128) f32 -> out NHWC (64,128,64,64) bf16. stride2 pad1.
__global__ __launch_bounds__(256) void conv1_k(
    const float* __restrict__ d, const float* __restrict__ w,
    const float* __restrict__ bias, __hip_bfloat16* __restrict__ out)
{
    __shared__ float in_s[3][66];
    __shared__ float ws_[576];
    __shared__ float bs_[64];
    int tid = threadIdx.x;
    int owhalf = blockIdx.x & 1;
    int oh = (blockIdx.x >> 1) & 127;
    int b  = blockIdx.x >> 8;
    int owbase = owhalf * 32;

    for (int l = tid; l < 576; l += 256) ws_[l] = w[l];
    if (tid < 64) bs_[tid] = bias[tid];
    for (int l = tid; l < 3 * 66; l += 256) {
        int r = l / 66, c = l % 66;
        int ih = 2 * oh - 1 + r;
        int iw = 2 * owbase - 1 + c;
        float v = 0.f;
        if ((unsigned)ih < 256u && (unsigned)iw < 128u)
            v = d[(b * 256 + ih) * 128 + iw];
        in_s[r][c] = v;
    }
    __syncthreads();

    int owl = tid >> 3, ocg = tid & 7;
    float in9[9];
#pragma unroll
    for (int r = 0; r < 3; ++r)
#pragma unroll
        for (int c = 0; c < 3; ++c)
            in9[r * 3 + c] = in_s[r][2 * owl + c];

    short8 res;
#pragma unroll
    for (int j = 0; j < 8; ++j) {
        int oc = ocg * 8 + j;
        float a = bs_[oc];
#pragma unroll
        for (int s = 0; s < 9; ++s) a = fmaf(in9[s], ws_[oc * 9 + s], a);
        union { __hip_bfloat16 h; short s; } u;
        u.h = __float2bfloat16(a);
        res[j] = u.s;
    }
    long pos = ((long)(b * 128 + oh) * 64 + owbase + owl);
    *(short8*)((short*)out + pos * 64 + ocg * 8) = res;
}

// conv2 MFMA: M-tile 128, full k=64 staged per s: 18 barriers total.
__global__ __launch_bounds__(256) void conv2_mfma(
    const __hip_bfloat16* __restrict__ in, const __hip_bfloat16* __restrict__ w2t,
    const float* __restrict__ bias, __hip_bfloat16* __restrict__ out)
{
    __shared__ short A_lds[128][72];
    __shared__ short B_lds[128][72];
    int tid = threadIdx.x;
    int oh0 = blockIdx.x * 4;
    int b   = blockIdx.y;
    int lane = tid & 63, wave = tid >> 6;
    int l16 = lane & 15, lh = lane >> 4;
    const short* inp = (const short*)in;
    const short* w2p = (const short*)w2t;

    floatx4 acc[2][8] = {};

    for (int s = 0; s < 9; ++s) {
        int kh = s / 3, kw = s - kh * 3;
        short8 av[4], bv[4];
#pragma unroll
        for (int i = 0; i < 4; ++i) {
            int c = tid + i * 256;
            int pos = c >> 3, seg = c & 7;
            int ohl = pos >> 5, ow = pos & 31;
            int ih = 2 * (oh0 + ohl) - 1 + kh;
            int iw = 2 * ow - 1 + kw;
            short8 v = {0,0,0,0,0,0,0,0};
            if ((unsigned)ih < 128u && (unsigned)iw < 64u)
                v = *(const short8*)(inp + (((long)(b * 128 + ih) * 64 + iw) * 64 + seg * 8));
            av[i] = v;
            bv[i] = *(const short8*)(w2p + pos * 576 + s * 64 + seg * 8);
        }
        __syncthreads();
#pragma unroll
        for (int i = 0; i < 4; ++i) {
            int c = tid + i * 256;
            int pos = c >> 3, seg = c & 7;
            *(short8*)&A_lds[pos][seg * 8] = av[i];
            *(short8*)&B_lds[pos][seg * 8] = bv[i];
        }
        __syncthreads();
#pragma unroll
        for (int half = 0; half < 2; ++half) {
            short8 a0 = *(const short8*)&A_lds[wave * 32 + l16][half * 32 + lh * 8];
            short8 a1 = *(const short8*)&A_lds[wave * 32 + 16 + l16][half * 32 + lh * 8];
#pragma unroll
            for (int ni = 0; ni < 8; ++ni) {
                short8 bvf = *(const short8*)&B_lds[ni * 16 + l16][half * 32 + lh * 8];
                acc[0][ni] = MFMA16(a0, bvf, acc[0][ni]);
                acc[1][ni] = MFMA16(a1, bvf, acc[1][ni]);
            }
        }
    }

    float bf[8];
#pragma unroll
    for (int ni = 0; ni < 8; ++ni) bf[ni] = bias[ni * 16 + l16];
#pragma unroll
    for (int mi = 0; mi < 2; ++mi)
#pragma unroll
        for (int r = 0; r < 4; ++r) {
            int m = wave * 32 + mi * 16 + lh * 4 + r;
            int ohl = m >> 5, ow = m & 31;
            __hip_bfloat16* op = out + (((long)(b * 64 + oh0 + ohl) * 32) + ow) * 128;
#pragma unroll
            for (int ni = 0; ni < 8; ++ni) {
                int oc = ni * 16 + l16;
                op[oc] = __float2bfloat16(acc[mi][ni][r] + bf[ni]);
            }
        }
}

// conv3 MFMA: M-tile 64, full k=128 staged per s: 18 barriers total.
__global__ __launch_bounds__(256) void conv3_mfma(
    const __hip_bfloat16* __restrict__ in, const __hip_bfloat16* __restrict__ w3t,
    const float* __restrict__ bias, float* __restrict__ dep)
{
    __shared__ short A_lds[64][136];
    __shared__ short B_lds[128][136];
    int tid = threadIdx.x;
    int oh0 = blockIdx.x * 4;
    int b   = blockIdx.y;
    int lane = tid & 63, wave = tid >> 6;
    int wr = wave >> 1, wc = wave & 1;
    int l16 = lane & 15, lh = lane >> 4;
    const short* inp = (const short*)in;
    const short* w3p = (const short*)w3t;

    floatx4 acc[2][4] = {};

    for (int s = 0; s < 9; ++s) {
        int kh = s / 3, kw = s - kh * 3;
        short8 av[4], bv[8];
#pragma unroll
        for (int i = 0; i < 4; ++i) {
            int c = tid + i * 256;
            int pos = c >> 4, seg = c & 15;
            int oa = pos >> 4, ow = pos & 15;
            int ih = 2 * (oh0 + oa) - 1 + kh;
            int iw = 2 * ow - 1 + kw;
            short8 v = {0,0,0,0,0,0,0,0};
            if ((unsigned)ih < 64u && (unsigned)iw < 32u)
                v = *(const short8*)(inp + (((long)(b * 64 + ih) * 32 + iw) * 128 + seg * 8));
            av[i] = v;
        }
#pragma unroll
        for (int i = 0; i < 8; ++i) {
            int c = tid + i * 256;
            int oc = c >> 4, seg = c & 15;
            bv[i] = *(const short8*)(w3p + oc * 1152 + s * 128 + seg * 8);
        }
        __syncthreads();
#pragma unroll
        for (int i = 0; i < 4; ++i) {
            int c = tid + i * 256;
            int pos = c >> 4, seg = c & 15;
            *(short8*)&A_lds[pos][seg * 8] = av[i];
        }
#pragma unroll
        for (int i = 0; i < 8; ++i) {
            int c = tid + i * 256;
            int oc = c >> 4, seg = c & 15;
            *(short8*)&B_lds[oc][seg * 8] = bv[i];
        }
        __syncthreads();
#pragma unroll
        for (int ks = 0; ks < 4; ++ks) {
            short8 a0 = *(const short8*)&A_lds[wr * 32 + l16][ks * 32 + lh * 8];
            short8 a1 = *(const short8*)&A_lds[wr * 32 + 16 + l16][ks * 32 + lh * 8];
#pragma unroll
            for (int ni = 0; ni < 4; ++ni) {
                short8 bvf = *(const short8*)&B_lds[wc * 64 + ni * 16 + l16][ks * 32 + lh * 8];
                acc[0][ni] = MFMA16(a0, bvf, acc[0][ni]);
                acc[1][ni] = MFMA16(a1, bvf, acc[1][ni]);
            }
        }
    }

    float bf[4];
#pragma unroll
    for (int ni = 0; ni < 4; ++ni) bf[ni] = bias[wc * 64 + ni * 16 + l16];
#pragma unroll
    for (int mi = 0; mi < 2; ++mi)
#pragma unroll
        for (int r = 0; r < 4; ++r) {
            int m = wr * 32 + mi * 16 + lh * 4 + r;
            int oa2 = m >> 4, ow2 = m & 15;
            float* op = dep + ((long)b * 512 + (oh0 + oa2) * 16 + ow2) * 128;
#pragma unroll
            for (int ni = 0; ni < 4; ++ni) {
                int oc = wc * 64 + ni * 16 + l16;
                op[oc] = acc[mi][ni][r] + bf[ni];
            }
        }
}

// v = dep @ W_mv + c0v via bf16 MFMA hi/lo split (~fp32 accuracy).
__global__ __launch_bounds__(256) void vgemm_mfma(
    const float* __restrict__ dep, const __hip_bfloat16* __restrict__ Bh,
    const __hip_bfloat16* __restrict__ Bl, const float* __restrict__ c0v,
    float* __restrict__ v)
{
    __shared__ short Ah[64][136];
    __shared__ short Al[64][136];
    int tid = threadIdx.x;
    int m0 = blockIdx.x * 64;

    for (int l4 = tid; l4 < 64 * 32; l4 += 256) {
        int r = l4 >> 5, c4 = l4 & 31;
        const float* sp = dep + ((long)(m0 + r) << 7) + c4 * 4;
        shortx4 hv, lv;
#pragma unroll
        for (int i = 0; i < 4; ++i) {
            float f = sp[i];
            union { __hip_bfloat16 b; short s; } uh, ul;
            uh.b = __float2bfloat16(f);
            ul.b = __float2bfloat16(f - __bfloat162float(uh.b));
            hv[i] = uh.s; lv[i] = ul.s;
        }
        *(shortx4*)&Ah[r][c4 * 4] = hv;
        *(shortx4*)&Al[r][c4 * 4] = lv;
    }
    __syncthreads();

    int lane = tid & 63, wave = tid >> 6;
    int wr = wave >> 1, wc = wave & 1;
    int l16 = lane & 15, lh = lane >> 4;
    floatx4 acc[2][4] = {};
#pragma unroll
    for (int kk = 0; kk < 4; ++kk) {
        short8 ah[2], al[2];
#pragma unroll
        for (int mi = 0; mi < 2; ++mi) {
            ah[mi] = *(const short8*)&Ah[wr * 32 + mi * 16 + l16][kk * 32 + lh * 8];
            al[mi] = *(const short8*)&Al[wr * 32 + mi * 16 + l16][kk * 32 + lh * 8];
        }
#pragma unroll
        for (int nf = 0; nf < 4; ++nf) {
            int gn = wc * 64 + nf * 16 + l16;
            short8 bh = *(const short8*)((const short*)Bh + gn * 128 + kk * 32 + lh * 8);
            short8 bl = *(const short8*)((const short*)Bl + gn * 128 + kk * 32 + lh * 8);
#pragma unroll
            for (int mi = 0; mi < 2; ++mi) {
                acc[mi][nf] = MFMA16(ah[mi], bh, acc[mi][nf]);
                acc[mi][nf] = MFMA16(al[mi], bh, acc[mi][nf]);
                acc[mi][nf] = MFMA16(ah[mi], bl, acc[mi][nf]);
            }
        }
    }
#pragma unroll
    for (int nf = 0; nf < 4; ++nf) {
        int gn = wc * 64 + nf * 16 + l16;
        float cv = c0v[gn];
#pragma unroll
        for (int mi = 0; mi < 2; ++mi)
#pragma unroll
            for (int r = 0; r < 4; ++r) {
                int m = m0 + wr * 32 + mi * 16 + lh * 4 + r;
                v[(long)m * 128 + gn] = acc[mi][nf][r] + cv;
            }
    }
}

// sel: MFMA hi/lo GEMM (8192 x 80pad x 768) + fused sigmoid + softmax.
__global__ __launch_bounds__(256) void selmfma_k(
    const float* __restrict__ F, const __hip_bfloat16* __restrict__ Wbh,
    const __hip_bfloat16* __restrict__ Wbl, const float* __restrict__ rowbias,
    float* __restrict__ lx, float* __restrict__ ly, float* __restrict__ attn)
{
    __shared__ short Ah[16][136];
    __shared__ short Al[16][136];
    int tid = threadIdx.x;
    int m0 = blockIdx.x * 16;
    int padd = (m0 >> 7) + 1;
    int lane = tid & 63, wave = tid >> 6;
    int l16 = lane & 15, lh = lane >> 4;

    int sr = tid >> 4, sc = (tid & 15) * 8;
    const float* fsrc = F + (long)(m0 + sr + padd) * 768 + sc;

    floatx4 acc0 = {0.f, 0.f, 0.f, 0.f};
    floatx4 acc1 = {0.f, 0.f, 0.f, 0.f};
    bool two = (wave == 3);
    const short* bhp = (const short*)Wbh;
    const short* blp = (const short*)Wbl;
    int gn0 = wave * 16 + l16;
    int gn1 = 64 + l16;

    for (int c = 0; c < 6; ++c) {
        __syncthreads();
        float4 f0 = *(const float4*)(fsrc + c * 128);
        float4 f1 = *(const float4*)(fsrc + c * 128 + 4);
        shortx4 h0, l0, h1, l1;
#pragma unroll
        for (int i = 0; i < 4; ++i) {
            union { __hip_bfloat16 b; short s; } uh, ul;
            float fa = (&f0.x)[i];
            uh.b = __float2bfloat16(fa);
            ul.b = __float2bfloat16(fa - __bfloat162float(uh.b));
            h0[i] = uh.s; l0[i] = ul.s;
            float fb = (&f1.x)[i];
            uh.b = __float2bfloat16(fb);
            ul.b = __float2bfloat16(fb - __bfloat162float(uh.b));
            h1[i] = uh.s; l1[i] = ul.s;
        }
        *(shortx4*)&Ah[sr][sc]     = h0;
        *(shortx4*)&Ah[sr][sc + 4] = h1;
        *(shortx4*)&Al[sr][sc]     = l0;
        *(shortx4*)&Al[sr][sc + 4] = l1;
        __syncthreads();
#pragma unroll
        for (int ks = 0; ks < 4; ++ks) {
            short8 ah = *(const short8*)&Ah[l16][ks * 32 + lh * 8];
            short8 al = *(const short8*)&Al[l16][ks * 32 + lh * 8];
            int koff = c * 128 + ks * 32 + lh * 8;
            short8 bh0 = *(const short8*)(bhp + gn0 * 768 + koff);
            short8 bl0 = *(const short8*)(blp + gn0 * 768 + koff);
            acc0 = MFMA16(ah, bh0, acc0);
            acc0 = MFMA16(al, bh0, acc0);
            acc0 = MFMA16(ah, bl0, acc0);
            if (two) {
                short8 bh1 = *(const short8*)(bhp + gn1 * 768 + koff);
                short8 bl1 = *(const short8*)(blp + gn1 * 768 + koff);
                acc1 = MFMA16(ah, bh1, acc1);
                acc1 = MFMA16(al, bh1, acc1);
                acc1 = MFMA16(ah, bl1, acc1);
            }
        }
    }

    if (wave < 3) {
        int j = wave * 16 + l16;
#pragma unroll
        for (int r = 0; r < 4; ++r) {
            int row = m0 + lh * 4 + r;
            float val = acc0[r] + rowbias[(row >> 7) * 72 + j];
            float sg = 1.f / (1.f + expf(-val));
            if (j & 1) ly[row * 24 + (j >> 1)] = sg;
            else       lx[row * 24 + (j >> 1)] = sg;
        }
    } else {
#pragma unroll
        for (int r = 0; r < 4; ++r) {
            int row = m0 + lh * 4 + r;
            int b72 = (row >> 7) * 72;
            float s0 = 1.f / (1.f + expf(-(acc0[r] + rowbias[b72 + 48 + l16])));
            float s1 = -1e30f;
            if (l16 < 8)
                s1 = 1.f / (1.f + expf(-(acc1[r] + rowbias[b72 + 64 + l16])));
            float mx = fmaxf(s0, s1);
#pragma unroll
            for (int s = 1; s < 16; s <<= 1)
                mx = fmaxf(mx, __shfl_xor(mx, s));
            float e0 = expf(s0 - mx);
            float e1 = (l16 < 8) ? expf(s1 - mx) : 0.f;
            float sum = e0 + e1;
#pragma unroll
            for (int s = 1; s < 16; s <<= 1)
                sum += __shfl_xor(sum, s);
            attn[row * 24 + l16] = e0 / sum;
            if (l16 < 8) attn[row * 24 + 16 + l16] = e1 / sum;
        }
    }
}

// bw_k: per-(row,k) bilinear gather offsets + folded weights (attn*coeff/24).
__global__ __launch_bounds__(256) void bw_k(
    const float* __restrict__ lx, const float* __restrict__ ly,
    const float* __restrict__ attn, int* __restrict__ idxb,
    float* __restrict__ wtb)
{
    int e = blockIdx.x * 256 + threadIdx.x;    // 8192*24 = 196608
    if (e >= 8192 * 24) return;
    float lxv = lx[e], lyv = ly[e], a = attn[e] * (1.f / 24.f);
    float x1 = floorf(lxv * 15.f), x2 = fminf(x1 + 1.f, 15.f);
    float y1 = floorf(lyv * 31.f), y2 = fminf(y1 + 1.f, 31.f);
    int xi1 = (int)x1, xi2 = (int)x2, yi1 = (int)y1, yi2 = (int)y2;
    float x = lxv * 16.f, y = lyv * 32.f;
    float w_ = x2 - x1, h_ = y2 - y1;
    float hwp = h_ * w_;
    bool deg = (h_ == 0.f) || (w_ == 0.f);
    float denom = (hwp == 0.f) ? 1.f : hwp;
    float coeff = (deg ? 2.f : 1.f / denom) * a;
    float xv0 = (w_ == 0.f) ? 1.f : (x2 - x);
    float xv1 = (w_ == 0.f) ? 1.f : (x - x1);
    float yv0 = (h_ == 0.f) ? 1.f : (y2 - y);
    float yv1 = (h_ == 0.f) ? 1.f : (y - y1);
    idxb[e * 4 + 0] = (xi1 * 16 + yi2) * 128;
    idxb[e * 4 + 1] = (xi2 * 16 + yi2) * 128;
    idxb[e * 4 + 2] = (xi2 * 16 + yi1) * 128;
    idxb[e * 4 + 3] = (xi1 * 16 + yi1) * 128;
    wtb[e * 4 + 0] = coeff * xv0 * yv0;
    wtb[e * 4 + 1] = coeff * xv0 * yv1;
    wtb[e * 4 + 2] = coeff * xv1 * yv0;
    wtb[e * 4 + 3] = coeff * xv1 * yv1;
}

// r2d gather: 4 coalesced loads + 4 FMAs per keypoint, weights from LDS.
__global__ __launch_bounds__(128) void r2d_k(
    const float* __restrict__ v, const int* __restrict__ idxb,
    const float* __restrict__ wtb, float* __restrict__ r2d)
{
    int n = blockIdx.x;
    int b = blockIdx.y;
    int c = threadIdx.x;
    int row = b * 128 + n;
    __shared__ int sidx[96];
    __shared__ float swt[96];
    if (c < 96) {
        sidx[c] = idxb[(long)row * 96 + c];
        swt[c]  = wtb[(long)row * 96 + c];
    }
    __syncthreads();
    const float* vb = v + (long)b * 512 * 128 + c;
    float acc = 0.f;
#pragma unroll
    for (int k = 0; k < 24; ++k) {
        acc = fmaf(swt[k * 4 + 0], vb[sidx[k * 4 + 0]], acc);
        acc = fmaf(swt[k * 4 + 1], vb[sidx[k * 4 + 1]], acc);
        acc = fmaf(swt[k * 4 + 2], vb[sidx[k * 4 + 2]], acc);
        acc = fmaf(swt[k * 4 + 3], vb[sidx[k * 4 + 3]], acc);
    }
    r2d[(long)row * 128 + c] = acc;
}

// final_embedding[b,c] = mean over n of r2d
__global__ __launch_bounds__(128) void fe_k(const float* __restrict__ r2d,
                                            float* __restrict__ fe)
{
    int b = blockIdx.x;
    int c = threadIdx.x;
    float acc = 0.f;
    for (int nn = 0; nn < 128; ++nn) acc += r2d[((long)b * 128 + nn) * 128 + c];
    fe[b * 128 + c] = acc * (1.f / 128.f);
}

// cls_score = fe @ W_cls, thread-per-output
__global__ __launch_bounds__(256) void cls_k(
    const float* __restrict__ fe, const float* __restrict__ W_cls,
    float* __restrict__ out)
{
    int idx = blockIdx.x * 256 + threadIdx.x;
    if (idx >= 64 * 751) return;
    int m = idx / 751, n = idx - m * 751;
    const float* fr = fe + m * 128;
    float acc = 0.f;
    for (int k = 0; k < 128; ++k)
        acc = fmaf(fr[k], W_cls[k * 751 + n], acc);
    out[idx] = acc;
}

extern "C" void kernel_launch(void* const* d_in, const int* in_sizes, int n_in,
                              void* d_out, int out_size, void* d_ws, size_t ws_size,
                              hipStream_t stream)
{
    const float* features = (const float*)d_in[0];
    const float* d        = (const float*)d_in[1];
    const float* W_rg  = (const float*)d_in[2];
    const float* b_rg  = (const float*)d_in[3];
    const float* W_rl  = (const float*)d_in[4];
    const float* b_rl  = (const float*)d_in[5];
    const float* c1w   = (const float*)d_in[6];
    const float* c1b   = (const float*)d_in[7];
    const float* c2w   = (const float*)d_in[8];
    const float* c2b   = (const float*)d_in[9];
    const float* c3w   = (const float*)d_in[10];
    const float* c3b   = (const float*)d_in[11];
    const float* g_depth = (const float*)d_in[12];
    const float* W_merge = (const float*)d_in[13];
    const float* b_merge = (const float*)d_in[14];
    const float* W_q   = (const float*)d_in[15];
    const float* b_q   = (const float*)d_in[16];
    const float* W_v   = (const float*)d_in[17];
    const float* b_v   = (const float*)d_in[18];
    const float* W_sel = (const float*)d_in[19];
    const float* b_sel = (const float*)d_in[20];
    const float* W_cls = (const float*)d_in[21];
    float* out = (float*)d_out;

    char* ws = (char*)d_ws;
    __hip_bfloat16* c1 = (__hip_bfloat16*)(ws + 0);            // NHWC, ws[0 .. 67,108,864)
    float* dep    = (float*)(ws + 0);                          // 16,777,216 (c1 dead after conv2)
    float* v      = (float*)(ws + 33554432);                   // 16,777,216
    __hip_bfloat16* c2 = (__hip_bfloat16*)(ws + 67108864);     // NHWC 33,554,432
    __hip_bfloat16* w2t = (__hip_bfloat16*)(ws + 100663296);          // 147,456
    __hip_bfloat16* w3t = (__hip_bfloat16*)(ws + 100810752);          // 294,912
    // folded-weight buffers: dead gap, untouched by convs
    float* W_qs    = (float*)(ws + 101105664);                 // 73,728
    float* W_mv    = (float*)(ws + 101179392);                 // 65,536
    float* W_big   = (float*)(ws + 101244928);                 // 221,184
    float* rowbias = (float*)(ws + 101466112);                 // 18,432
    float* c0b     = (float*)(ws + 101484544);                 // 512
    float* c0v     = (float*)(ws + 101485056);                 // 512
    float* gfeat   = (float*)(ws + 101485568);                 // 32,768
    __hip_bfloat16* Wmv_bh = (__hip_bfloat16*)(ws + 101518336);  // 32,768
    __hip_bfloat16* Wmv_bl = (__hip_bfloat16*)(ws + 101551104);  // 32,768
    __hip_bfloat16* Wbig_h = (__hip_bfloat16*)(ws + 101583872);  // 122,880
    __hip_bfloat16* Wbig_l = (__hip_bfloat16*)(ws + 101706752);  // 122,880 (ends 101,829,632)
    int*   idxb   = (int*)(ws + 101832704);                    // 3,145,728
    float* wtb    = (float*)(ws + 104978432);                  // 3,145,728 (ends 108,124,160)
    float* lxb    = (float*)(ws + 111411200);                  // 786,432
    float* lyb    = (float*)(ws + 112197632);                  // 786,432
    float* attnb  = (float*)(ws + 112984064);                  // 786,432
    float* r2d    = (float*)(ws + 113836544);                  // 4,194,304

    float* fe = out + 64 * 751;

    // ---- prep (folded weights) ----
    prep1_k<<<265, 256, 0, stream>>>(W_q, W_sel, W_merge, W_v, g_depth, b_merge,
                                     features, W_rg, b_rg, W_qs, W_mv, c0b, gfeat);
    prep2_k<<<289, 256, 0, stream>>>(W_rl, W_qs, W_sel, b_rl, b_q, b_sel,
                                     gfeat, c0b, W_v, b_v, W_big, rowbias, c0v);
    prep3_k<<<64, 256, 0, stream>>>(W_mv, Wmv_bh, Wmv_bl);
    prep4_k<<<240, 256, 0, stream>>>(W_big, Wbig_h, Wbig_l);
    wt2_k<<<288, 256, 0, stream>>>(c2w, w2t);
    wt3_k<<<576, 256, 0, stream>>>(c3w, w3t);

    // ---- conv path (MFMA) ----
    conv1_k<<<16384, 256, 0, stream>>>(d, c1w, c1b, c1);
    conv2_mfma<<<dim3(16, 64), 256, 0, stream>>>(c1, w2t, c2b, c2);
    conv3_mfma<<<dim3(8, 64), 256, 0, stream>>>(c2, w3t, c3b, dep);

    // v = dep @ W_mv + c0v   (MFMA hi/lo)
    vgemm_mfma<<<512, 256, 0, stream>>>(dep, Wmv_bh, Wmv_bl, c0v, v);
    // sel (MFMA hi/lo GEMM + sigmoid + softmax fused)
    selmfma_k<<<512, 256, 0, stream>>>(features, Wbig_h, Wbig_l, rowbias,
                                       lxb, lyb, attnb);
    // bilinear weight precompute
    bw_k<<<768, 256, 0, stream>>>(lxb, lyb, attnb, idxb, wtb);

    // ---- fusion tail ----
    r2d_k<<<dim3(128, 64), 128, 0, stream>>>(v, idxb, wtb, r2d);
    fe_k<<<64, 128, 0, stream>>>(r2d, fe);
    cls_k<<<188, 256, 0, stream>>>(fe, W_cls, out);
}